// Round 7
// baseline (592.567 us; speedup 1.0000x reference)
//
#include <hip/hip_runtime.h>
#include <hip/hip_bf16.h>
#include <math.h>

#define LAYERS 4
#define IDIM 256
#define HDIM 512
#define NH 8
#define HD 64
#define FF 1024
#define SEQ 1024
#define BATCH 8
#define EPS 1e-5f

typedef __attribute__((ext_vector_type(8))) short short8;
typedef __attribute__((ext_vector_type(4))) short short4v;
typedef __attribute__((ext_vector_type(4))) float f32x4;
typedef __attribute__((ext_vector_type(4))) int int4v;
typedef __attribute__((ext_vector_type(4))) unsigned int uint4v;
typedef unsigned long long u64;

// fp32 -> bf16 (RNE) on raw bits
__device__ __forceinline__ short f2bf(float f) {
    unsigned u = __float_as_uint(f);
    u = (u + 0x7FFFu + ((u >> 16) & 1u)) >> 16;
    return (short)u;
}
__device__ __forceinline__ float bf2f(short s) {
    return __uint_as_float(((unsigned)(unsigned short)s) << 16);
}
__device__ __forceinline__ void gll16(const void* g, void* l) {
    __builtin_amdgcn_global_load_lds(
        (const __attribute__((address_space(1))) unsigned int*)g,
        (__attribute__((address_space(3))) unsigned int*)l, 16, 0, 0);
}
// raw v_exp_f32 (2^x); exp2f may expand to a libm sequence
__device__ __forceinline__ float fexp2(float x) {
#if __has_builtin(__builtin_amdgcn_exp2f)
    return __builtin_amdgcn_exp2f(x);
#else
    return exp2f(x);
#endif
}

#define BAR() __builtin_amdgcn_s_barrier()
#define SCHED0() __builtin_amdgcn_sched_barrier(0)
#define VM4() asm volatile("s_waitcnt vmcnt(4)" ::: "memory")
#define VM0() asm volatile("s_waitcnt vmcnt(0)" ::: "memory")
#define LGKM0() asm volatile("s_waitcnt lgkmcnt(0)" ::: "memory")

// ---------------------------------------------------------------------------
// merged prep: weight cvt (8320 blocks) + nodes transpose (2048 blocks) +
// ballot-based mask build (8192 blocks, one per (b,q), coalesced dist reads).
#define CVT_P0 131072u
#define CVT_P1 3276800u
#define CVT_P2 4325376u
#define CVT_P3 6422528u
#define CVT_TOT 8519680u
#define PREP_W 8320
#define PREP_N 2048
__global__ __launch_bounds__(256) void prep_all(
    const float* __restrict__ s0, short* __restrict__ d0,
    const float* __restrict__ s1, short* __restrict__ d1,
    const float* __restrict__ s2, short* __restrict__ d2,
    const float* __restrict__ s3, short* __restrict__ d3,
    const float* __restrict__ s4, short* __restrict__ d4,
    const float* __restrict__ nodes, short* __restrict__ xt,
    const int* __restrict__ dist, u64* __restrict__ mS,
    u64* __restrict__ mL, u64* __restrict__ mG) {
    int blk = blockIdx.x;
    if (blk < PREP_W) {                     // weight fp32->bf16
        size_t i = ((size_t)blk * 256 + threadIdx.x) * 4;
        const float* s; short* d; size_t off;
        if (i < CVT_P0)      { s = s0; d = d0; off = i; }
        else if (i < CVT_P1) { s = s1; d = d1; off = i - CVT_P0; }
        else if (i < CVT_P2) { s = s2; d = d2; off = i - CVT_P1; }
        else if (i < CVT_P3) { s = s3; d = d3; off = i - CVT_P2; }
        else                 { s = s4; d = d4; off = i - CVT_P3; }
        f32x4 f = *(const f32x4*)(s + off);
        short4v o = {f2bf(f[0]), f2bf(f[1]), f2bf(f[2]), f2bf(f[3])};
        *(short4v*)(d + off) = o;
    } else if (blk < PREP_W + PREP_N) {     // nodes (S,B,I) -> (B*S,I) bf16
        size_t idx = ((size_t)(blk - PREP_W) * 256 + threadIdx.x) * 4;
        int i  = idx & (IDIM - 1);
        int sb = idx >> 8;
        int b  = sb & (BATCH - 1);
        int s  = sb >> 3;
        f32x4 f = *(const f32x4*)(nodes + idx);
        short4v o = {f2bf(f[0]), f2bf(f[1]), f2bf(f[2]), f2bf(f[3])};
        *(short4v*)(xt + ((size_t)b * SEQ + s) * IDIM + i) = o;
    } else {                                // ballot mask build, 1 blk per (b,q)
        int blk2 = blk - (PREP_W + PREP_N);
        int b = blk2 >> 10, q = blk2 & 1023;
        int wv = threadIdx.x >> 6, lane = threadIdx.x & 63;
        const int* dp = dist + ((size_t)b * SEQ + q) * SEQ;
        size_t mbase = ((size_t)b * SEQ + q) * 16;
#pragma unroll
        for (int it = 0; it < 4; it++) {
            int w64 = it * 4 + wv;
            int d = dp[w64 * 64 + lane];
            u64 bs = __ballot(d == 1);
            u64 bl = __ballot(d >= 1);
            if (lane == 0) {
                mS[mbase + w64] = bs;
                mL[mbase + w64] = bl;
                if (q == 0) mG[b * 16 + w64] = bl;
            }
        }
    }
}

// ---------------------------------------------------------------------------
// bf16 MFMA GEMM (16x16x32). BM x 128 tile. Used ONLY for QKV now; BK=128
// halves the barrier-drain count (4 K-steps at K=512, 64 MFMA per drain).
// V-blocks (n0>=1024) -> transposed Vt (B,NH,HD,S); K-blocks (512<=n0<1024)
// -> head-major Kt (B,NH,S,HD); Q-blocks -> C. Bias folded everywhere.
template<int BM, int BK>
__global__ __launch_bounds__(256, 2)
void gemm_bf16(const short* __restrict__ A, const short* __restrict__ W,
               const float* __restrict__ bias, short* __restrict__ C,
               short* __restrict__ vt, short* __restrict__ ktr,
               int M, int N, int K, int relu) {
    constexpr int UPR = BK / 8;        // 16B units per row
    constexpr int RPC = 512 / BK;      // rows per 1KB staging chunk
    __shared__ __align__(16) short As[BM * BK];
    __shared__ __align__(16) short Ws[128 * BK];
    const int tid = threadIdx.x;
    const int w = tid >> 6, lane = tid & 63;
    const int l15 = lane & 15, quad = lane >> 4;
    const int m0 = blockIdx.y * BM, n0 = blockIdx.x * 128;

    constexpr int NI = (BM == 128) ? 4 : 2;
    const int wm = (BM == 128) ? (w >> 1) * 64 : 0;
    const int wn = (BM == 128) ? (w & 1) * 64 : w * 32;

    f32x4 acc[4][NI];
#pragma unroll
    for (int mi = 0; mi < 4; mi++)
#pragma unroll
        for (int ni = 0; ni < NI; ni++) acc[mi][ni] = (f32x4){0.f, 0.f, 0.f, 0.f};

    const int r_in = (BK == 64) ? (lane >> 3) : (lane >> 4);
    const int c8   = lane & (UPR - 1);

    for (int k0 = 0; k0 < K; k0 += BK) {
#pragma unroll
        for (int rep = 0; rep < BM * BK / 2048; rep++) {
            int chunk = rep * 4 + w;
            int row = chunk * RPC + r_in;
            const short* src = A + (size_t)(m0 + row) * K + k0 + ((c8 ^ (row & (UPR - 1))) << 3);
            gll16(src, (char*)As + chunk * 1024);
        }
#pragma unroll
        for (int rep = 0; rep < 128 * BK / 2048; rep++) {
            int chunk = rep * 4 + w;
            int row = chunk * RPC + r_in;
            const short* src = W + (size_t)(n0 + row) * K + k0 + ((c8 ^ (row & (UPR - 1))) << 3);
            gll16(src, (char*)Ws + chunk * 1024);
        }
        __syncthreads();
#pragma unroll
        for (int ks = 0; ks < BK / 32; ks++) {
            short8 af[4], wf[NI];
            const int dblk = ks * 4 + quad;
#pragma unroll
            for (int mi = 0; mi < 4; mi++) {
                int row = wm + mi * 16 + l15;
                af[mi] = *(const short8*)((const char*)As + row * (BK * 2) + ((dblk ^ (row & (UPR - 1))) << 4));
            }
#pragma unroll
            for (int ni = 0; ni < NI; ni++) {
                int row = wn + ni * 16 + l15;
                wf[ni] = *(const short8*)((const char*)Ws + row * (BK * 2) + ((dblk ^ (row & (UPR - 1))) << 4));
            }
#pragma unroll
            for (int mi = 0; mi < 4; mi++)
#pragma unroll
                for (int ni = 0; ni < NI; ni++)
                    acc[mi][ni] = __builtin_amdgcn_mfma_f32_16x16x32_bf16(
                        af[mi], wf[ni], acc[mi][ni], 0, 0, 0);
        }
        __syncthreads();
    }
    if (vt && n0 >= 1024) {
        // V-projection epilogue: plain transpose into Vt (B,NH,HD,S)
#pragma unroll
        for (int ni = 0; ni < NI; ni++) {
            int n = n0 + wn + ni * 16 + l15;
            int d = n - 1024, h = d >> 6, dd = d & 63;
            float bz = bias[n];
#pragma unroll
            for (int mi = 0; mi < 4; mi++) {
                int mbase = m0 + wm + mi * 16 + quad * 4;   // 4 consecutive s
                int b = mbase >> 10, s = mbase & 1023;
                size_t off = ((size_t)(b * NH + h) * HD + dd) * SEQ + s;
                short4v pk;
#pragma unroll
                for (int r = 0; r < 4; r++) pk[r] = f2bf(acc[mi][ni][r] + bz);
                *(short4v*)(vt + off) = pk;
            }
        }
    } else if (ktr && n0 >= 512) {
        // K-projection epilogue: head-major Kt (B,NH,S,HD), bias folded
#pragma unroll
        for (int ni = 0; ni < NI; ni++) {
            int n = n0 + wn + ni * 16 + l15;
            int d = n - 512, h = d >> 6, dd = d & 63;
            float bz = bias[n];
#pragma unroll
            for (int mi = 0; mi < 4; mi++) {
                int mbase = m0 + wm + mi * 16 + quad * 4;   // 4 consecutive s
                int b = mbase >> 10, s = mbase & 1023;
                size_t base = ((size_t)(b * NH + h) * SEQ + s) * HD + dd;
#pragma unroll
                for (int r = 0; r < 4; r++)
                    ktr[base + (size_t)r * HD] = f2bf(acc[mi][ni][r] + bz);
            }
        }
    } else {
#pragma unroll
        for (int ni = 0; ni < NI; ni++) {
            int n = n0 + wn + ni * 16 + l15;
            float bz = bias[n];
#pragma unroll
            for (int mi = 0; mi < 4; mi++) {
#pragma unroll
                for (int r = 0; r < 4; r++) {
                    int m = m0 + wm + mi * 16 + quad * 4 + r;
                    float v = acc[mi][ni][r] + bz;
                    if (relu) v = fmaxf(v, 0.f);
                    C[(size_t)m * N + n] = f2bf(v);
                }
            }
        }
    }
}

// ---------------------------------------------------------------------------
// Fused full-row GEMM + bias + (residual) + LayerNorm, 3-buf counted-vmcnt
// W stream. BM=32 rows x 512 cols, 512 thr. A panel staged ONCE. W streamed
// in 32KB chunks (256 rows x 64 k, 128B rows + XOR-8 = conflict-free), ring
// of 3 buffers, ONE barrier per chunk, vmcnt(4) steady state (never 0).
// 8 MFMA + 8 ds_read_b128 per barrier. Swapped MFMA operands -> acc
// n-contiguous; fused LN epilogue.
template<int K, bool RES>
__global__ __launch_bounds__(512, 1)
void gemm_ln(const short* __restrict__ A, const short* __restrict__ W,
             const float* __restrict__ bias, const short* __restrict__ resid,
             const float* __restrict__ g, const float* __restrict__ bta,
             short* __restrict__ Y) {
    constexpr int NCH = K / 32;             // (K/64 ksteps) x 2 row-groups
    __shared__ __align__(16) char smem[K * 64 + 98304];
    char* Apan = smem;                      // 32 rows x K (16/32 KB)
    char* ring = smem + K * 64;             // 3 x 32KB
    float* red = (float*)smem;              // epilogue alias

    const int tid = threadIdx.x, w = tid >> 6, lane = tid & 63;
    const int l15 = lane & 15, quad = lane >> 4;
    const int m0 = blockIdx.x * 32;
    const int rin8 = lane >> 3, c8 = lane & 7;
    const int swz8 = (c8 ^ rin8) << 3;      // staging source swizzle (shorts)

    f32x4 acc[2][4];
#pragma unroll
    for (int mi = 0; mi < 2; mi++)
#pragma unroll
        for (int j = 0; j < 4; j++) acc[mi][j] = (f32x4){0.f, 0.f, 0.f, 0.f};

    // ---- A panel stage (once) ----
    if constexpr (K == 512) {
#pragma unroll
        for (int j = 0; j < 4; j++) {
            int row = j * 8 + w;
            gll16(A + (size_t)(m0 + row) * K + ((lane ^ (row & 7)) << 3),
                  Apan + row * 1024);
        }
    } else {  // K == 256: 2 rows per 1KB segment
#pragma unroll
        for (int j = 0; j < 2; j++) {
            int seg = j * 8 + w;
            int row = seg * 2 + (lane >> 5);
            gll16(A + (size_t)(m0 + row) * K + (((lane & 31) ^ (row & 7)) << 3),
                  Apan + seg * 1024);
        }
    }
#define GISS(c)                                                               \
    do {                                                                      \
        int rg_ = (c) & 1, kst_ = (c) >> 1;                                   \
        char* bp_ = ring + ((c) % 3) * 32768;                                 \
        _Pragma("unroll")                                                     \
        for (int j_ = 0; j_ < 4; j_++) {                                      \
            int seg_ = j_ * 8 + w;                                            \
            int ric_ = seg_ * 8 + rin8;                                       \
            gll16(W + (size_t)(rg_ * 256 + ric_) * K + kst_ * 64 + swz8,      \
                  bp_ + seg_ * 1024);                                         \
        }                                                                     \
    } while (0)

    GISS(0); GISS(1);
    VM4();              // A + chunk0 resident (chunk1 in flight)
    BAR(); SCHED0();

    for (int c = 0; c < NCH; c++) {
        if (c + 2 < NCH) GISS(c + 2);       // into buffer freed 2 iters ago
        {
            int kst = c >> 1, rg = c & 1;
            const char* bp = ring + (c % 3) * 32768;
#pragma unroll
            for (int ks = 0; ks < 2; ks++) {
                short8 af[2];
#pragma unroll
                for (int mi = 0; mi < 2; mi++) {
                    int ar = mi * 16 + l15;
                    af[mi] = *(const short8*)(Apan + ar * (K * 2) +
                        (((kst * 8 + ks * 4 + quad) ^ (ar & 7)) << 4));
                }
#pragma unroll
                for (int ni = 0; ni < 2; ni++) {
                    int rr = w * 32 + ni * 16 + l15;
                    short8 wf = *(const short8*)(bp + rr * 128 +
                        (((ks * 4 + quad) ^ (rr & 7)) << 4));
#pragma unroll
                    for (int mi = 0; mi < 2; mi++)
                        acc[mi][rg * 2 + ni] = __builtin_amdgcn_mfma_f32_16x16x32_bf16(
                            wf, af[mi], acc[mi][rg * 2 + ni], 0, 0, 0);
                }
            }
        }
        if (c + 1 < NCH) {
            if (c + 2 < NCH) VM4(); else VM0();
            BAR(); SCHED0();
        }
    }
#undef GISS
    __syncthreads();    // Apan/ring reads done everywhere before red reuse

    // ---- fused epilogue: bias (+residual) -> row stats -> LN -> store ----
    // layout: m = m0 + mi*16 + l15, n = (j>>1)*256 + w*32 + (j&1)*16 + quad*4
    float sum[2] = {0.f, 0.f}, sq[2] = {0.f, 0.f};
#pragma unroll
    for (int mi = 0; mi < 2; mi++)
#pragma unroll
        for (int j = 0; j < 4; j++) {
            int nb = (j >> 1) * 256 + w * 32 + (j & 1) * 16 + quad * 4;
            f32x4 bz = *(const f32x4*)(bias + nb);
            f32x4 v;
            if (RES) {
                short4v rv = *(const short4v*)(resid + (size_t)(m0 + mi * 16 + l15) * HDIM + nb);
#pragma unroll
                for (int r = 0; r < 4; r++) v[r] = acc[mi][j][r] + bz[r] + bf2f(rv[r]);
            } else {
#pragma unroll
                for (int r = 0; r < 4; r++) v[r] = acc[mi][j][r] + bz[r];
            }
            acc[mi][j] = v;
            sum[mi] += v[0] + v[1] + v[2] + v[3];
            sq[mi]  += v[0] * v[0] + v[1] * v[1] + v[2] * v[2] + v[3] * v[3];
        }
#pragma unroll
    for (int mi = 0; mi < 2; mi++) {
        sum[mi] += __shfl_xor(sum[mi], 16); sum[mi] += __shfl_xor(sum[mi], 32);
        sq[mi]  += __shfl_xor(sq[mi], 16);  sq[mi]  += __shfl_xor(sq[mi], 32);
    }
    if (quad == 0) {
#pragma unroll
        for (int mi = 0; mi < 2; mi++) {
            red[(mi * 16 + l15) * 8 + w]       = sum[mi];
            red[256 + (mi * 16 + l15) * 8 + w] = sq[mi];
        }
    }
    __syncthreads();
    float mean[2], inv[2];
#pragma unroll
    for (int mi = 0; mi < 2; mi++) {
        f32x4 s0 = *(const f32x4*)(red + (mi * 16 + l15) * 8);
        f32x4 s1 = *(const f32x4*)(red + (mi * 16 + l15) * 8 + 4);
        f32x4 q0 = *(const f32x4*)(red + 256 + (mi * 16 + l15) * 8);
        f32x4 q1 = *(const f32x4*)(red + 256 + (mi * 16 + l15) * 8 + 4);
        float st = s0[0] + s0[1] + s0[2] + s0[3] + s1[0] + s1[1] + s1[2] + s1[3];
        float qt = q0[0] + q0[1] + q0[2] + q0[3] + q1[0] + q1[1] + q1[2] + q1[3];
        float mn = st * (1.f / HDIM);
        float vr = qt * (1.f / HDIM) - mn * mn;
        mean[mi] = mn;
        inv[mi]  = rsqrtf(vr + EPS);
    }
#pragma unroll
    for (int mi = 0; mi < 2; mi++)
#pragma unroll
        for (int j = 0; j < 4; j++) {
            int nb = (j >> 1) * 256 + w * 32 + (j & 1) * 16 + quad * 4;
            f32x4 gv = *(const f32x4*)(g + nb);
            f32x4 bv = *(const f32x4*)(bta + nb);
            short4v pk;
#pragma unroll
            for (int r = 0; r < 4; r++)
                pk[r] = f2bf((acc[mi][j][r] - mean[mi]) * inv[mi] * gv[r] + bv[r]);
            *(short4v*)(Y + (size_t)(m0 + mi * 16 + l15) * HDIM + nb) = pk;
        }
}

// ---------------------------------------------------------------------------
// Fused FFN: Y = LN(X + relu(X*W1^T + b1)*W2^T + b2). BM=32, 512 thr.
// Phase 1: W1 streamed in 32KB chunks (3-buf ring, 1 barrier/chunk, vmcnt(4)).
// H -> LDS (64KB). Phase 2: H consumed from LDS, W2 streamed in the SAME
// 3-buf/1-barrier ring form (was 2-buf/2-barrier). LDS 160KB (gfx950 max):
// p1 = [X 32K | ring 96K @32K]; p2 = [H 64K | ring2 96K @64K].
// Residual X re-read from global in the epilogue (H overwrites the X panel).
__global__ __launch_bounds__(512, 1)
void fused_ffn(const short* __restrict__ X, const short* __restrict__ W1,
               const float* __restrict__ b1, const short* __restrict__ W2,
               const float* __restrict__ b2, const float* __restrict__ g,
               const float* __restrict__ bta, short* __restrict__ Y) {
    __shared__ __align__(16) char smem[163840];
    char* Apan  = smem;                     // 32KB: X panel (phase 1)
    char* ring  = smem + 32768;             // 96KB: 3 x 32KB (phase 1)
    char* Hs    = smem;                     // 64KB: H (phase 2)
    char* ring2 = smem + 65536;             // 96KB: 3 x 32KB (phase 2)
    float* red  = (float*)(smem + 65536);   // epilogue alias (ring2 buf0 free)

    const int tid = threadIdx.x, w = tid >> 6, lane = tid & 63;
    const int l15 = lane & 15, quad = lane >> 4;
    const int m0 = blockIdx.x * 32;
    const int rin8 = lane >> 3, c8 = lane & 7;
    const int swz8 = (c8 ^ rin8) << 3;

    // ---------------- phase 1: H = relu(X*W1^T + b1), 32 x 1024 ----------
    f32x4 acc1[2][8];
#pragma unroll
    for (int mi = 0; mi < 2; mi++)
#pragma unroll
        for (int j = 0; j < 8; j++) acc1[mi][j] = (f32x4){0.f, 0.f, 0.f, 0.f};

#pragma unroll
    for (int j = 0; j < 4; j++) {           // X panel (32 x 512)
        int row = j * 8 + w;
        gll16(X + (size_t)(m0 + row) * HDIM + ((lane ^ (row & 7)) << 3),
              Apan + row * 1024);
    }
#define F1ISS(c)                                                              \
    do {                                                                      \
        int rg_ = (c) & 3, kst_ = (c) >> 2;                                   \
        char* bp_ = ring + ((c) % 3) * 32768;                                 \
        _Pragma("unroll")                                                     \
        for (int j_ = 0; j_ < 4; j_++) {                                      \
            int seg_ = j_ * 8 + w;                                            \
            int ric_ = seg_ * 8 + rin8;                                       \
            gll16(W1 + (size_t)(rg_ * 256 + ric_) * HDIM + kst_ * 64 + swz8,  \
                  bp_ + seg_ * 1024);                                         \
        }                                                                     \
    } while (0)
#define F2ISS(c)                                                              \
    do {                                                                      \
        int rg_ = (c) & 1, kst_ = (c) >> 1;                                   \
        char* bp_ = ring2 + ((c) % 3) * 32768;                                \
        _Pragma("unroll")                                                     \
        for (int j_ = 0; j_ < 4; j_++) {                                      \
            int seg_ = j_ * 8 + w;                                            \
            int ric_ = seg_ * 8 + rin8;                                       \
            gll16(W2 + (size_t)(rg_ * 256 + ric_) * FF + kst_ * 64 + swz8,    \
                  bp_ + seg_ * 1024);                                         \
        }                                                                     \
    } while (0)

    F1ISS(0); F1ISS(1);
    VM4();
    BAR(); SCHED0();

    for (int c = 0; c < 32; c++) {          // 8 ksteps x 4 row-groups
        if (c + 2 < 32) F1ISS(c + 2);
        {
            int kst = c >> 2, rg = c & 3;
            const char* bp = ring + (c % 3) * 32768;
#pragma unroll
            for (int ks = 0; ks < 2; ks++) {
                short8 af[2];
#pragma unroll
                for (int mi = 0; mi < 2; mi++) {
                    int ar = mi * 16 + l15;
                    af[mi] = *(const short8*)(Apan + ar * 1024 +
                        (((kst * 8 + ks * 4 + quad) ^ (ar & 7)) << 4));
                }
#pragma unroll
                for (int ni = 0; ni < 2; ni++) {
                    int rr = w * 32 + ni * 16 + l15;
                    short8 wf = *(const short8*)(bp + rr * 128 +
                        (((ks * 4 + quad) ^ (rr & 7)) << 4));
#pragma unroll
                    for (int mi = 0; mi < 2; mi++)
                        acc1[mi][rg * 2 + ni] = __builtin_amdgcn_mfma_f32_16x16x32_bf16(
                            wf, af[mi], acc1[mi][rg * 2 + ni], 0, 0, 0);
                }
            }
        }
        if (c + 1 < 32) {
            if (c + 2 < 32) VM4(); else VM0();
            BAR(); SCHED0();
        }
    }
    __syncthreads();        // all waves done with Apan + ring

    // ---- transition: prefetch W2 chunks 0,1; park H in LDS ---------------
    F2ISS(0); F2ISS(1);
    // H write: row = mi*16+l15 (2048B rows), n = (j>>1)*256+w*32+(j&1)*16+quad*4
#pragma unroll
    for (int mi = 0; mi < 2; mi++)
#pragma unroll
        for (int j = 0; j < 8; j++) {
            int n = (j >> 1) * 256 + w * 32 + (j & 1) * 16 + quad * 4;
            f32x4 bz = *(const f32x4*)(b1 + n);
            short4v pk;
#pragma unroll
            for (int r = 0; r < 4; r++)
                pk[r] = f2bf(fmaxf(acc1[mi][j][r] + bz[r], 0.f));
            int row = mi * 16 + l15;
            int u = n >> 3;
            *(short4v*)(Hs + row * 2048 + ((u ^ (row & 7)) << 4) + (quad & 1) * 8) = pk;
        }
    LGKM0();                // own H stores drained
    VM4();                  // W2 chunk 0 resident (chunk 1 flying)
    BAR(); SCHED0();

    // ---------------- phase 2: Y = LN(H*W2^T + b2 + X) --------------------
    f32x4 acc2[2][4];
#pragma unroll
    for (int mi = 0; mi < 2; mi++)
#pragma unroll
        for (int j = 0; j < 4; j++) acc2[mi][j] = (f32x4){0.f, 0.f, 0.f, 0.f};

    for (int c = 0; c < 32; c++) {          // 16 ksteps x 2 row-groups
        if (c + 2 < 32) F2ISS(c + 2);       // into buffer freed 2 iters ago
        {
            int kst = c >> 1, rg = c & 1;
            const char* bp = ring2 + (c % 3) * 32768;
#pragma unroll
            for (int ks = 0; ks < 2; ks++) {
                short8 af[2];
#pragma unroll
                for (int mi = 0; mi < 2; mi++) {
                    int ar = mi * 16 + l15;
                    af[mi] = *(const short8*)(Hs + ar * 2048 +
                        (((kst * 8 + ks * 4 + quad) ^ (ar & 7)) << 4));
                }
#pragma unroll
                for (int ni = 0; ni < 2; ni++) {
                    int rr = w * 32 + ni * 16 + l15;
                    short8 wf = *(const short8*)(bp + rr * 128 +
                        (((ks * 4 + quad) ^ (rr & 7)) << 4));
#pragma unroll
                    for (int mi = 0; mi < 2; mi++)
                        acc2[mi][rg * 2 + ni] = __builtin_amdgcn_mfma_f32_16x16x32_bf16(
                            wf, af[mi], acc2[mi][rg * 2 + ni], 0, 0, 0);
                }
            }
        }
        if (c + 1 < 32) {
            if (c + 2 < 32) VM4(); else VM0();
            BAR(); SCHED0();
        }
    }
#undef F1ISS
#undef F2ISS
    __syncthreads();        // ring2 reads done everywhere before red reuse

    // ---- epilogue: bias + residual(X, global) -> LN -> store -------------
    float sum[2] = {0.f, 0.f}, sq[2] = {0.f, 0.f};
#pragma unroll
    for (int mi = 0; mi < 2; mi++)
#pragma unroll
        for (int j = 0; j < 4; j++) {
            int nb = (j >> 1) * 256 + w * 32 + (j & 1) * 16 + quad * 4;
            f32x4 bz = *(const f32x4*)(b2 + nb);
            short4v rv = *(const short4v*)(X + (size_t)(m0 + mi * 16 + l15) * HDIM + nb);
            f32x4 v;
#pragma unroll
            for (int r = 0; r < 4; r++) v[r] = acc2[mi][j][r] + bz[r] + bf2f(rv[r]);
            acc2[mi][j] = v;
            sum[mi] += v[0] + v[1] + v[2] + v[3];
            sq[mi]  += v[0] * v[0] + v[1] * v[1] + v[2] * v[2] + v[3] * v[3];
        }
#pragma unroll
    for (int mi = 0; mi < 2; mi++) {
        sum[mi] += __shfl_xor(sum[mi], 16); sum[mi] += __shfl_xor(sum[mi], 32);
        sq[mi]  += __shfl_xor(sq[mi], 16);  sq[mi]  += __shfl_xor(sq[mi], 32);
    }
    if (quad == 0) {
#pragma unroll
        for (int mi = 0; mi < 2; mi++) {
            red[(mi * 16 + l15) * 8 + w]       = sum[mi];
            red[256 + (mi * 16 + l15) * 8 + w] = sq[mi];
        }
    }
    __syncthreads();
    float mean[2], inv[2];
#pragma unroll
    for (int mi = 0; mi < 2; mi++) {
        f32x4 s0 = *(const f32x4*)(red + (mi * 16 + l15) * 8);
        f32x4 s1 = *(const f32x4*)(red + (mi * 16 + l15) * 8 + 4);
        f32x4 q0 = *(const f32x4*)(red + 256 + (mi * 16 + l15) * 8);
        f32x4 q1 = *(const f32x4*)(red + 256 + (mi * 16 + l15) * 8 + 4);
        float st = s0[0] + s0[1] + s0[2] + s0[3] + s1[0] + s1[1] + s1[2] + s1[3];
        float qt = q0[0] + q0[1] + q0[2] + q0[3] + q1[0] + q1[1] + q1[2] + q1[3];
        float mn = st * (1.f / HDIM);
        float vr = qt * (1.f / HDIM) - mn * mn;
        mean[mi] = mn;
        inv[mi]  = rsqrtf(vr + EPS);
    }
#pragma unroll
    for (int mi = 0; mi < 2; mi++)
#pragma unroll
        for (int j = 0; j < 4; j++) {
            int nb = (j >> 1) * 256 + w * 32 + (j & 1) * 16 + quad * 4;
            f32x4 gv = *(const f32x4*)(g + nb);
            f32x4 bv = *(const f32x4*)(bta + nb);
            short4v pk;
#pragma unroll
            for (int r = 0; r < 4; r++)
                pk[r] = f2bf((acc2[mi][j][r] - mean[mi]) * inv[mi] * gv[r] + bv[r]);
            *(short4v*)(Y + (size_t)(m0 + mi * 16 + l15) * HDIM + nb) = pk;
        }
}

// ---------------------------------------------------------------------------
// MFMA flash attention. Key-permuted K staging makes S^T's C-layout directly a
// K=32 B-frag for PV (16x16x32, full-rate, zero shuffles). K staged from
// head-major Kt (B,NH,S,HD): 128B-contiguous key rows -> 8 cache lines per
// gll16. 128-key tile per barrier pair.
#define EXP2SC 0.18033688011112042f   /* 0.125 * log2(e) */
__global__ __launch_bounds__(256, 4)
void attn_mfma(const short* __restrict__ qkv, const short* __restrict__ ktr,
               const short* __restrict__ vt,
               const u64* __restrict__ maskS, const u64* __restrict__ maskL,
               const u64* __restrict__ maskG, short* __restrict__ out) {
    const int tid = threadIdx.x;
    const int w = tid >> 6, lane = tid & 63, l15 = lane & 15, quad = lane >> 4;
    const int p = blockIdx.x;
    const int g_ = (p & 7) + 8 * (p >> 7);          // (b,h) group, XCD-swizzled
    const int qt = (p >> 3) & 15;
    const int b = g_ >> 3, h = g_ & 7;
    const int q = qt * 64 + w * 16 + l15;

    __shared__ __align__(16) short Ks[128 * 64];    // 128 keys (permuted) x 64 d
    __shared__ __align__(16) short Vs[128 * 64];    // 2 halves: 64 d x 64 keys

    short8 qf[2];
    {
        const short* qrow = qkv + ((size_t)(b * SEQ + q) * 1536) + h * 64;
#pragma unroll
        for (int ks = 0; ks < 2; ks++)
            qf[ks] = *(const short8*)(qrow + ks * 32 + quad * 8);
    }
    const u64* mrow = (h < 4) ? (maskS + ((size_t)b * SEQ + q) * 16)
                   : (h < 6) ? (maskL + ((size_t)b * SEQ + q) * 16)
                   :           (maskG + (size_t)b * 16);

    f32x4 of[4];
#pragma unroll
    for (int mt = 0; mt < 4; mt++) of[mt] = (f32x4){0.f, 0.f, 0.f, 0.f};
    float ls0 = 0.f, ls1 = 0.f;

    const int r_in = lane >> 3, c8 = lane & 7;
    const int swz = (c8 ^ r_in) << 3;   // chunk-invariant staging swizzle
    const short* kbase = ktr + ((size_t)(b * NH + h) * SEQ) * HD + swz;
    const short* vp = vt + ((size_t)((b * NH + h) * HD) + r_in) * SEQ + swz;
    const int fsw = (l15 & 7);

    for (int kt = 0; kt < SEQ; kt += 128) {
#pragma unroll
        for (int rep = 0; rep < 4; rep++) {         // K: permuted rows
            int c = rep * 4 + w;
            int pr = c * 8 + r_in;                  // physical staged row
            int pt = pr & 63;
            int key = (pr & 64) | (pt & 32) | (((pt >> 2) & 3) << 3)
                    | (((pt >> 4) & 1) << 2) | (pt & 3);
            gll16(kbase + (size_t)(kt + key) * HD, (char*)Ks + c * 1024);
        }
#pragma unroll
        for (int rep = 0; rep < 4; rep++) {         // V: plain, 2 halves x 8
            int v = rep * 4 + w;
            gll16(vp + (size_t)((v & 7) * 8) * SEQ + kt + (v >> 3) * 64,
                  (char*)Vs + v * 1024);
        }
        __syncthreads();

#pragma unroll
        for (int t = 0; t < 2; t++) {
            // S^T sub-tile (64 permuted keys x 16 q)
            f32x4 sa[4];
#pragma unroll
            for (int g = 0; g < 4; g++) sa[g] = (f32x4){0.f, 0.f, 0.f, 0.f};
#pragma unroll
            for (int ks = 0; ks < 2; ks++) {
                const int dblk = ks * 4 + quad;
#pragma unroll
                for (int g = 0; g < 4; g++) {
                    int row = t * 64 + g * 16 + l15;
                    short8 kf = *(const short8*)((const char*)Ks + row * 128 + ((dblk ^ fsw) << 4));
                    sa[g] = __builtin_amdgcn_mfma_f32_16x16x32_bf16(kf, qf[ks], sa[g], 0, 0, 0);
                }
            }
            // masked softmax numerator (max-free); logical bitpos for slot
            // (g,quad,r) is quad*8 + (g>>1)*32 + (g&1)*4 + r
            u64 mw = mrow[(kt >> 6) + t];
            if ((q >> 6) == (kt >> 6) + t) mw |= 1ull << (q & 63);
            u64 mq2 = mw >> (quad * 8);
            unsigned mlo = (unsigned)mq2, mhi = (unsigned)(mq2 >> 32);
            float pv[4][4];
#pragma unroll
            for (int g = 0; g < 4; g++) {
                unsigned mg = ((g & 2) ? mhi : mlo) >> ((g & 1) * 4);
#pragma unroll
                for (int r = 0; r < 4; r++) {
                    float e = fexp2(sa[g][r] * EXP2SC);
                    e = ((mg >> r) & 1u) ? e : 0.f;
                    pv[g][r] = e;
                    if (g & 1) ls1 += e; else ls0 += e;
                }
            }
            // pack C reg-pairs directly into K=32 B-frags (no shuffles)
            short8 pfrag[2];
#pragma unroll
            for (int g32 = 0; g32 < 2; g32++) {
                uint4v pk;
                pk[0] = __builtin_amdgcn_perm(__float_as_uint(pv[2 * g32][1]),
                                              __float_as_uint(pv[2 * g32][0]), 0x07060302u);
                pk[1] = __builtin_amdgcn_perm(__float_as_uint(pv[2 * g32][3]),
                                              __float_as_uint(pv[2 * g32][2]), 0x07060302u);
                pk[2] = __builtin_amdgcn_perm(__float_as_uint(pv[2 * g32 + 1][1]),
                                              __float_as_uint(pv[2 * g32 + 1][0]), 0x07060302u);
                pk[3] = __builtin_amdgcn_perm(__float_as_uint(pv[2 * g32 + 1][3]),
                                              __float_as_uint(pv[2 * g32 + 1][2]), 0x07060302u);
                pfrag[g32] = __builtin_bit_cast(short8, pk);
            }
            // O^T += V^T . P^T  (16x16x32, 8 MFMAs per sub-tile)
#pragma unroll
            for (int g32 = 0; g32 < 2; g32++) {
                const int u = g32 * 4 + quad;
#pragma unroll
                for (int mt = 0; mt < 4; mt++) {
                    int row = mt * 16 + l15;
                    short8 vf = *(const short8*)((const char*)Vs + t * 8192 + row * 128 + ((u ^ fsw) << 4));
                    of[mt] = __builtin_amdgcn_mfma_f32_16x16x32_bf16(vf, pfrag[g32], of[mt], 0, 0, 0);
                }
            }
        }
        __syncthreads();
    }
    float lsum = ls0 + ls1;
    lsum += __shfl_xor(lsum, 16);
    lsum += __shfl_xor(lsum, 32);
    float inv = 1.f / lsum;              // diagonal always allowed -> lsum > 0
#pragma unroll
    for (int mt = 0; mt < 4; mt++) {
        short4v pk;
#pragma unroll
        for (int r = 0; r < 4; r++) pk[r] = f2bf(of[mt][r] * inv);
        *(short4v*)(out + ((size_t)(b * SEQ + q) * HDIM) + h * 64 + mt * 16 + quad * 4) = pk;
    }
}

// ---------------------------------------------------------------------------
__global__ __launch_bounds__(256) void final_bn(const short* __restrict__ X,
                                                const float* __restrict__ g,
                                                const float* __restrict__ bb,
                                                float* __restrict__ out) {
    int h = blockIdx.x * 256 + threadIdx.x;
    if (h >= HDIM) return;
    float vals[BATCH];
    float m = 0.f;
#pragma unroll
    for (int b = 0; b < BATCH; b++) {
        vals[b] = bf2f(X[(size_t)b * SEQ * HDIM + h]);
        m += vals[b];
    }
    m *= (1.f / BATCH);
    float v = 0.f;
#pragma unroll
    for (int b = 0; b < BATCH; b++) { float d = vals[b] - m; v += d * d; }
    v *= (1.f / BATCH);
    float inv = rsqrtf(v + EPS);
#pragma unroll
    for (int b = 0; b < BATCH; b++)
        out[b * HDIM + h] = (vals[b] - m) * inv * g[h] + bb[h];
}

// ---------------------------------------------------------------------------
extern "C" void kernel_launch(void* const* d_in, const int* in_sizes, int n_in,
                              void* d_out, int out_size, void* d_ws, size_t ws_size,
                              hipStream_t stream) {
    const float* nodes      = (const float*)d_in[0];
    const int*   dist       = (const int*)  d_in[1];
    const float* dense_w    = (const float*)d_in[2];
    const float* dense_b    = (const float*)d_in[3];
    const float* dense_ln_g = (const float*)d_in[4];
    const float* dense_ln_b = (const float*)d_in[5];
    const float* qkv_w      = (const float*)d_in[6];
    const float* qkv_b      = (const float*)d_in[7];
    const float* out_w      = (const float*)d_in[8];
    const float* out_b      = (const float*)d_in[9];
    const float* ln1_g      = (const float*)d_in[10];
    const float* ln1_b      = (const float*)d_in[11];
    const float* ffn_w1     = (const float*)d_in[12];
    const float* ffn_b1     = (const float*)d_in[13];
    const float* ffn_w2     = (const float*)d_in[14];
    const float* ffn_b2     = (const float*)d_in[15];
    const float* ln2_g      = (const float*)d_in[16];
    const float* ln2_b      = (const float*)d_in[17];
    const float* bn_g       = (const float*)d_in[18];
    const float* bn_b       = (const float*)d_in[19];
    float* out = (float*)d_out;

    const int M = BATCH * SEQ;                         // 8192
    const size_t MB = 1024 * 1024;
    char* ws = (char*)d_ws;
    short* Wd   = (short*)(ws + 0 * MB);
    short* Wqkv = (short*)(ws + 1 * MB);
    short* Wo   = (short*)(ws + 9 * MB);
    short* W1   = (short*)(ws + 13 * MB);
    short* W2   = (short*)(ws + 18 * MB);
    u64*   mS   = (u64*)(ws + 23 * MB);
    u64*   mL   = (u64*)(ws + 24 * MB);
    u64*   mG   = (u64*)(ws + 25 * MB);
    short* X    = (short*)(ws + 26 * MB);
    short* QKV  = (short*)(ws + 34 * MB);
    short* Vt   = (short*)(ws + 58 * MB);
    short* AT   = (short*)(ws + 66 * MB);
    short* Kt   = (short*)(ws + 74 * MB);
    short* XT   = QKV;

    prep_all<<<PREP_W + PREP_N + BATCH * SEQ, 256, 0, stream>>>(
        dense_w, Wd, qkv_w, Wqkv, out_w, Wo, ffn_w1, W1, ffn_w2, W2,
        nodes, XT, dist, mS, mL, mG);

    // dense projection + dense LN, fused
    gemm_ln<IDIM, false><<<M / 32, 512, 0, stream>>>(
        XT, Wd, dense_b, nullptr, dense_ln_g, dense_ln_b, X);

    for (int l = 0; l < LAYERS; l++) {
        const short* wqkv = Wqkv + (size_t)l * 3 * HDIM * HDIM;
        const float* bqkv = qkv_b + (size_t)l * 3 * HDIM;
        const short* wo   = Wo + (size_t)l * HDIM * HDIM;
        const float* bo   = out_b + (size_t)l * HDIM;
        const short* w1   = W1 + (size_t)l * FF * HDIM;
        const float* b1   = ffn_b1 + (size_t)l * FF;
        const short* w2   = W2 + (size_t)l * HDIM * FF;
        const float* b2   = ffn_b2 + (size_t)l * HDIM;

        gemm_bf16<128, 128><<<dim3(3 * HDIM / 128, M / 128), 256, 0, stream>>>(
            X, wqkv, bqkv, QKV, Vt, Kt, M, 3 * HDIM, HDIM, 0);
        attn_mfma<<<1024, 256, 0, stream>>>(QKV, Kt, Vt, mS, mL, mG, AT);
        // attn out projection + residual + LN1, fused
        gemm_ln<HDIM, true><<<M / 32, 512, 0, stream>>>(
            AT, wo, bo, X, ln1_g + l * HDIM, ln1_b + l * HDIM, X);
        // FFN up + relu + down + residual + LN2, fully fused (no F1 buffer)
        fused_ffn<<<M / 32, 512, 0, stream>>>(
            X, w1, b1, w2, b2, ln2_g + l * HDIM, ln2_b + l * HDIM, X);
    }
    final_bn<<<(HDIM + 255) / 256, 256, 0, stream>>>(X, bn_g, bn_b, out);
}

// Round 8
// 560.356 us; speedup vs baseline: 1.0575x; 1.0575x over previous
//
#include <hip/hip_runtime.h>
#include <hip/hip_bf16.h>
#include <math.h>

#define LAYERS 4
#define IDIM 256
#define HDIM 512
#define NH 8
#define HD 64
#define FF 1024
#define SEQ 1024
#define BATCH 8
#define EPS 1e-5f

typedef __attribute__((ext_vector_type(8))) short short8;
typedef __attribute__((ext_vector_type(4))) short short4v;
typedef __attribute__((ext_vector_type(4))) float f32x4;
typedef __attribute__((ext_vector_type(4))) int int4v;
typedef __attribute__((ext_vector_type(4))) unsigned int uint4v;
typedef unsigned long long u64;

// fp32 -> bf16 (RNE) on raw bits
__device__ __forceinline__ short f2bf(float f) {
    unsigned u = __float_as_uint(f);
    u = (u + 0x7FFFu + ((u >> 16) & 1u)) >> 16;
    return (short)u;
}
__device__ __forceinline__ float bf2f(short s) {
    return __uint_as_float(((unsigned)(unsigned short)s) << 16);
}
__device__ __forceinline__ void gll16(const void* g, void* l) {
    __builtin_amdgcn_global_load_lds(
        (const __attribute__((address_space(1))) unsigned int*)g,
        (__attribute__((address_space(3))) unsigned int*)l, 16, 0, 0);
}
// raw v_exp_f32 (2^x); exp2f may expand to a libm sequence
__device__ __forceinline__ float fexp2(float x) {
#if __has_builtin(__builtin_amdgcn_exp2f)
    return __builtin_amdgcn_exp2f(x);
#else
    return exp2f(x);
#endif
}

#define BAR() __builtin_amdgcn_s_barrier()
#define SCHED0() __builtin_amdgcn_sched_barrier(0)
#define VM4() asm volatile("s_waitcnt vmcnt(4)" ::: "memory")
#define VM0() asm volatile("s_waitcnt vmcnt(0)" ::: "memory")
#define LGKM0() asm volatile("s_waitcnt lgkmcnt(0)" ::: "memory")

// ---------------------------------------------------------------------------
// merged prep: weight cvt (8320 blocks) + nodes transpose (2048 blocks) +
// ballot-based mask build (8192 blocks, one per (b,q), coalesced dist reads).
#define CVT_P0 131072u
#define CVT_P1 3276800u
#define CVT_P2 4325376u
#define CVT_P3 6422528u
#define CVT_TOT 8519680u
#define PREP_W 8320
#define PREP_N 2048
__global__ __launch_bounds__(256) void prep_all(
    const float* __restrict__ s0, short* __restrict__ d0,
    const float* __restrict__ s1, short* __restrict__ d1,
    const float* __restrict__ s2, short* __restrict__ d2,
    const float* __restrict__ s3, short* __restrict__ d3,
    const float* __restrict__ s4, short* __restrict__ d4,
    const float* __restrict__ nodes, short* __restrict__ xt,
    const int* __restrict__ dist, u64* __restrict__ mS,
    u64* __restrict__ mL, u64* __restrict__ mG) {
    int blk = blockIdx.x;
    if (blk < PREP_W) {                     // weight fp32->bf16
        size_t i = ((size_t)blk * 256 + threadIdx.x) * 4;
        const float* s; short* d; size_t off;
        if (i < CVT_P0)      { s = s0; d = d0; off = i; }
        else if (i < CVT_P1) { s = s1; d = d1; off = i - CVT_P0; }
        else if (i < CVT_P2) { s = s2; d = d2; off = i - CVT_P1; }
        else if (i < CVT_P3) { s = s3; d = d3; off = i - CVT_P2; }
        else                 { s = s4; d = d4; off = i - CVT_P3; }
        f32x4 f = *(const f32x4*)(s + off);
        short4v o = {f2bf(f[0]), f2bf(f[1]), f2bf(f[2]), f2bf(f[3])};
        *(short4v*)(d + off) = o;
    } else if (blk < PREP_W + PREP_N) {     // nodes (S,B,I) -> (B*S,I) bf16
        size_t idx = ((size_t)(blk - PREP_W) * 256 + threadIdx.x) * 4;
        int i  = idx & (IDIM - 1);
        int sb = idx >> 8;
        int b  = sb & (BATCH - 1);
        int s  = sb >> 3;
        f32x4 f = *(const f32x4*)(nodes + idx);
        short4v o = {f2bf(f[0]), f2bf(f[1]), f2bf(f[2]), f2bf(f[3])};
        *(short4v*)(xt + ((size_t)b * SEQ + s) * IDIM + i) = o;
    } else {                                // ballot mask build, 1 blk per (b,q)
        int blk2 = blk - (PREP_W + PREP_N);
        int b = blk2 >> 10, q = blk2 & 1023;
        int wv = threadIdx.x >> 6, lane = threadIdx.x & 63;
        const int* dp = dist + ((size_t)b * SEQ + q) * SEQ;
        size_t mbase = ((size_t)b * SEQ + q) * 16;
#pragma unroll
        for (int it = 0; it < 4; it++) {
            int w64 = it * 4 + wv;
            int d = dp[w64 * 64 + lane];
            u64 bs = __ballot(d == 1);
            u64 bl = __ballot(d >= 1);
            if (lane == 0) {
                mS[mbase + w64] = bs;
                mL[mbase + w64] = bl;
                if (q == 0) mG[b * 16 + w64] = bl;
            }
        }
    }
}

// ---------------------------------------------------------------------------
// bf16 MFMA GEMM (16x16x32). BM x 128 tile. Used ONLY for QKV now; BK=128
// halves the barrier-drain count (4 K-steps at K=512, 64 MFMA per drain) —
// R7-measured ~14us/layer win. V-blocks (n0>=1024) -> transposed Vt
// (B,NH,HD,S); K-blocks (512<=n0<1024) -> head-major Kt (B,NH,S,HD);
// Q-blocks -> C. Bias folded everywhere.
template<int BM, int BK>
__global__ __launch_bounds__(256, 2)
void gemm_bf16(const short* __restrict__ A, const short* __restrict__ W,
               const float* __restrict__ bias, short* __restrict__ C,
               short* __restrict__ vt, short* __restrict__ ktr,
               int M, int N, int K, int relu) {
    constexpr int UPR = BK / 8;        // 16B units per row
    constexpr int RPC = 512 / BK;      // rows per 1KB staging chunk
    __shared__ __align__(16) short As[BM * BK];
    __shared__ __align__(16) short Ws[128 * BK];
    const int tid = threadIdx.x;
    const int w = tid >> 6, lane = tid & 63;
    const int l15 = lane & 15, quad = lane >> 4;
    const int m0 = blockIdx.y * BM, n0 = blockIdx.x * 128;

    constexpr int NI = (BM == 128) ? 4 : 2;
    const int wm = (BM == 128) ? (w >> 1) * 64 : 0;
    const int wn = (BM == 128) ? (w & 1) * 64 : w * 32;

    f32x4 acc[4][NI];
#pragma unroll
    for (int mi = 0; mi < 4; mi++)
#pragma unroll
        for (int ni = 0; ni < NI; ni++) acc[mi][ni] = (f32x4){0.f, 0.f, 0.f, 0.f};

    const int r_in = (BK == 64) ? (lane >> 3) : (lane >> 4);
    const int c8   = lane & (UPR - 1);

    for (int k0 = 0; k0 < K; k0 += BK) {
#pragma unroll
        for (int rep = 0; rep < BM * BK / 2048; rep++) {
            int chunk = rep * 4 + w;
            int row = chunk * RPC + r_in;
            const short* src = A + (size_t)(m0 + row) * K + k0 + ((c8 ^ (row & (UPR - 1))) << 3);
            gll16(src, (char*)As + chunk * 1024);
        }
#pragma unroll
        for (int rep = 0; rep < 128 * BK / 2048; rep++) {
            int chunk = rep * 4 + w;
            int row = chunk * RPC + r_in;
            const short* src = W + (size_t)(n0 + row) * K + k0 + ((c8 ^ (row & (UPR - 1))) << 3);
            gll16(src, (char*)Ws + chunk * 1024);
        }
        __syncthreads();
#pragma unroll
        for (int ks = 0; ks < BK / 32; ks++) {
            short8 af[4], wf[NI];
            const int dblk = ks * 4 + quad;
#pragma unroll
            for (int mi = 0; mi < 4; mi++) {
                int row = wm + mi * 16 + l15;
                af[mi] = *(const short8*)((const char*)As + row * (BK * 2) + ((dblk ^ (row & (UPR - 1))) << 4));
            }
#pragma unroll
            for (int ni = 0; ni < NI; ni++) {
                int row = wn + ni * 16 + l15;
                wf[ni] = *(const short8*)((const char*)Ws + row * (BK * 2) + ((dblk ^ (row & (UPR - 1))) << 4));
            }
#pragma unroll
            for (int mi = 0; mi < 4; mi++)
#pragma unroll
                for (int ni = 0; ni < NI; ni++)
                    acc[mi][ni] = __builtin_amdgcn_mfma_f32_16x16x32_bf16(
                        af[mi], wf[ni], acc[mi][ni], 0, 0, 0);
        }
        __syncthreads();
    }
    if (vt && n0 >= 1024) {
        // V-projection epilogue: plain transpose into Vt (B,NH,HD,S)
#pragma unroll
        for (int ni = 0; ni < NI; ni++) {
            int n = n0 + wn + ni * 16 + l15;
            int d = n - 1024, h = d >> 6, dd = d & 63;
            float bz = bias[n];
#pragma unroll
            for (int mi = 0; mi < 4; mi++) {
                int mbase = m0 + wm + mi * 16 + quad * 4;   // 4 consecutive s
                int b = mbase >> 10, s = mbase & 1023;
                size_t off = ((size_t)(b * NH + h) * HD + dd) * SEQ + s;
                short4v pk;
#pragma unroll
                for (int r = 0; r < 4; r++) pk[r] = f2bf(acc[mi][ni][r] + bz);
                *(short4v*)(vt + off) = pk;
            }
        }
    } else if (ktr && n0 >= 512) {
        // K-projection epilogue: head-major Kt (B,NH,S,HD), bias folded
#pragma unroll
        for (int ni = 0; ni < NI; ni++) {
            int n = n0 + wn + ni * 16 + l15;
            int d = n - 512, h = d >> 6, dd = d & 63;
            float bz = bias[n];
#pragma unroll
            for (int mi = 0; mi < 4; mi++) {
                int mbase = m0 + wm + mi * 16 + quad * 4;   // 4 consecutive s
                int b = mbase >> 10, s = mbase & 1023;
                size_t base = ((size_t)(b * NH + h) * SEQ + s) * HD + dd;
#pragma unroll
                for (int r = 0; r < 4; r++)
                    ktr[base + (size_t)r * HD] = f2bf(acc[mi][ni][r] + bz);
            }
        }
    } else {
#pragma unroll
        for (int ni = 0; ni < NI; ni++) {
            int n = n0 + wn + ni * 16 + l15;
            float bz = bias[n];
#pragma unroll
            for (int mi = 0; mi < 4; mi++) {
#pragma unroll
                for (int r = 0; r < 4; r++) {
                    int m = m0 + wm + mi * 16 + quad * 4 + r;
                    float v = acc[mi][ni][r] + bz;
                    if (relu) v = fmaxf(v, 0.f);
                    C[(size_t)m * N + n] = f2bf(v);
                }
            }
        }
    }
}

// ---------------------------------------------------------------------------
// Fused full-row GEMM + bias + (residual) + LayerNorm, 3-buf counted-vmcnt
// W stream. BM=32 rows x 512 cols, 512 thr. A panel staged ONCE. W streamed
// in 32KB chunks (256 rows x 64 k, 128B rows + XOR-8 = conflict-free), ring
// of 3 buffers, ONE barrier per chunk, vmcnt(4) steady state (never 0).
// 8 MFMA + 8 ds_read_b128 per barrier. Swapped MFMA operands -> acc
// n-contiguous; fused LN epilogue.
template<int K, bool RES>
__global__ __launch_bounds__(512, 1)
void gemm_ln(const short* __restrict__ A, const short* __restrict__ W,
             const float* __restrict__ bias, const short* __restrict__ resid,
             const float* __restrict__ g, const float* __restrict__ bta,
             short* __restrict__ Y) {
    constexpr int NCH = K / 32;             // (K/64 ksteps) x 2 row-groups
    __shared__ __align__(16) char smem[K * 64 + 98304];
    char* Apan = smem;                      // 32 rows x K (16/32 KB)
    char* ring = smem + K * 64;             // 3 x 32KB
    float* red = (float*)smem;              // epilogue alias

    const int tid = threadIdx.x, w = tid >> 6, lane = tid & 63;
    const int l15 = lane & 15, quad = lane >> 4;
    const int m0 = blockIdx.x * 32;
    const int rin8 = lane >> 3, c8 = lane & 7;
    const int swz8 = (c8 ^ rin8) << 3;      // staging source swizzle (shorts)

    f32x4 acc[2][4];
#pragma unroll
    for (int mi = 0; mi < 2; mi++)
#pragma unroll
        for (int j = 0; j < 4; j++) acc[mi][j] = (f32x4){0.f, 0.f, 0.f, 0.f};

    // ---- A panel stage (once) ----
    if constexpr (K == 512) {
#pragma unroll
        for (int j = 0; j < 4; j++) {
            int row = j * 8 + w;
            gll16(A + (size_t)(m0 + row) * K + ((lane ^ (row & 7)) << 3),
                  Apan + row * 1024);
        }
    } else {  // K == 256: 2 rows per 1KB segment
#pragma unroll
        for (int j = 0; j < 2; j++) {
            int seg = j * 8 + w;
            int row = seg * 2 + (lane >> 5);
            gll16(A + (size_t)(m0 + row) * K + (((lane & 31) ^ (row & 7)) << 3),
                  Apan + seg * 1024);
        }
    }
#define GISS(c)                                                               \
    do {                                                                      \
        int rg_ = (c) & 1, kst_ = (c) >> 1;                                   \
        char* bp_ = ring + ((c) % 3) * 32768;                                 \
        _Pragma("unroll")                                                     \
        for (int j_ = 0; j_ < 4; j_++) {                                      \
            int seg_ = j_ * 8 + w;                                            \
            int ric_ = seg_ * 8 + rin8;                                       \
            gll16(W + (size_t)(rg_ * 256 + ric_) * K + kst_ * 64 + swz8,      \
                  bp_ + seg_ * 1024);                                         \
        }                                                                     \
    } while (0)

    GISS(0); GISS(1);
    VM4();              // A + chunk0 resident (chunk1 in flight)
    BAR(); SCHED0();

    for (int c = 0; c < NCH; c++) {
        if (c + 2 < NCH) GISS(c + 2);       // into buffer freed 2 iters ago
        {
            int kst = c >> 1, rg = c & 1;
            const char* bp = ring + (c % 3) * 32768;
#pragma unroll
            for (int ks = 0; ks < 2; ks++) {
                short8 af[2];
#pragma unroll
                for (int mi = 0; mi < 2; mi++) {
                    int ar = mi * 16 + l15;
                    af[mi] = *(const short8*)(Apan + ar * (K * 2) +
                        (((kst * 8 + ks * 4 + quad) ^ (ar & 7)) << 4));
                }
#pragma unroll
                for (int ni = 0; ni < 2; ni++) {
                    int rr = w * 32 + ni * 16 + l15;
                    short8 wf = *(const short8*)(bp + rr * 128 +
                        (((ks * 4 + quad) ^ (rr & 7)) << 4));
#pragma unroll
                    for (int mi = 0; mi < 2; mi++)
                        acc[mi][rg * 2 + ni] = __builtin_amdgcn_mfma_f32_16x16x32_bf16(
                            wf, af[mi], acc[mi][rg * 2 + ni], 0, 0, 0);
                }
            }
        }
        if (c + 1 < NCH) {
            if (c + 2 < NCH) VM4(); else VM0();
            BAR(); SCHED0();
        }
    }
#undef GISS
    __syncthreads();    // Apan/ring reads done everywhere before red reuse

    // ---- fused epilogue: bias (+residual) -> row stats -> LN -> store ----
    // layout: m = m0 + mi*16 + l15, n = (j>>1)*256 + w*32 + (j&1)*16 + quad*4
    float sum[2] = {0.f, 0.f}, sq[2] = {0.f, 0.f};
#pragma unroll
    for (int mi = 0; mi < 2; mi++)
#pragma unroll
        for (int j = 0; j < 4; j++) {
            int nb = (j >> 1) * 256 + w * 32 + (j & 1) * 16 + quad * 4;
            f32x4 bz = *(const f32x4*)(bias + nb);
            f32x4 v;
            if (RES) {
                short4v rv = *(const short4v*)(resid + (size_t)(m0 + mi * 16 + l15) * HDIM + nb);
#pragma unroll
                for (int r = 0; r < 4; r++) v[r] = acc[mi][j][r] + bz[r] + bf2f(rv[r]);
            } else {
#pragma unroll
                for (int r = 0; r < 4; r++) v[r] = acc[mi][j][r] + bz[r];
            }
            acc[mi][j] = v;
            sum[mi] += v[0] + v[1] + v[2] + v[3];
            sq[mi]  += v[0] * v[0] + v[1] * v[1] + v[2] * v[2] + v[3] * v[3];
        }
#pragma unroll
    for (int mi = 0; mi < 2; mi++) {
        sum[mi] += __shfl_xor(sum[mi], 16); sum[mi] += __shfl_xor(sum[mi], 32);
        sq[mi]  += __shfl_xor(sq[mi], 16);  sq[mi]  += __shfl_xor(sq[mi], 32);
    }
    if (quad == 0) {
#pragma unroll
        for (int mi = 0; mi < 2; mi++) {
            red[(mi * 16 + l15) * 8 + w]       = sum[mi];
            red[256 + (mi * 16 + l15) * 8 + w] = sq[mi];
        }
    }
    __syncthreads();
    float mean[2], inv[2];
#pragma unroll
    for (int mi = 0; mi < 2; mi++) {
        f32x4 s0 = *(const f32x4*)(red + (mi * 16 + l15) * 8);
        f32x4 s1 = *(const f32x4*)(red + (mi * 16 + l15) * 8 + 4);
        f32x4 q0 = *(const f32x4*)(red + 256 + (mi * 16 + l15) * 8);
        f32x4 q1 = *(const f32x4*)(red + 256 + (mi * 16 + l15) * 8 + 4);
        float st = s0[0] + s0[1] + s0[2] + s0[3] + s1[0] + s1[1] + s1[2] + s1[3];
        float qt = q0[0] + q0[1] + q0[2] + q0[3] + q1[0] + q1[1] + q1[2] + q1[3];
        float mn = st * (1.f / HDIM);
        float vr = qt * (1.f / HDIM) - mn * mn;
        mean[mi] = mn;
        inv[mi]  = rsqrtf(vr + EPS);
    }
#pragma unroll
    for (int mi = 0; mi < 2; mi++)
#pragma unroll
        for (int j = 0; j < 4; j++) {
            int nb = (j >> 1) * 256 + w * 32 + (j & 1) * 16 + quad * 4;
            f32x4 gv = *(const f32x4*)(g + nb);
            f32x4 bv = *(const f32x4*)(bta + nb);
            short4v pk;
#pragma unroll
            for (int r = 0; r < 4; r++)
                pk[r] = f2bf((acc[mi][j][r] - mean[mi]) * inv[mi] * gv[r] + bv[r]);
            *(short4v*)(Y + (size_t)(m0 + mi * 16 + l15) * HDIM + nb) = pk;
        }
}

// ---------------------------------------------------------------------------
// Fused FFN: Y = LN(X + relu(X*W1^T + b1)*W2^T + b2). BM=32, 512 thr.
// Phase 1: W1 streamed in 32KB chunks (3-buf ring, 1 barrier/chunk, vmcnt(4)).
// H -> LDS (64KB). Phase 2: H consumed from LDS, W2 streamed (2-buf,
// 2-barrier — R5-proven; the R7 3-buf/160KB variant regressed 40->59us).
// LDS 128KB: p1 = [X 32K | ring 96K]; p2 = [H 64K | 2x32K W2 bufs].
// Residual X re-read from global in the epilogue (H overwrites the X panel).
__global__ __launch_bounds__(512, 1)
void fused_ffn(const short* __restrict__ X, const short* __restrict__ W1,
               const float* __restrict__ b1, const short* __restrict__ W2,
               const float* __restrict__ b2, const float* __restrict__ g,
               const float* __restrict__ bta, short* __restrict__ Y) {
    __shared__ __align__(16) char smem[131072];
    char* Apan = smem;                      // 32KB: X panel (phase 1)
    char* ring = smem + 32768;              // 96KB: 3 x 32KB (phase 1)
    char* Hs   = smem;                      // 64KB: H (phase 2)
    char* W2b  = smem + 65536;              // 64KB: 2 x 32KB (phase 2)
    float* red = (float*)(smem + 65536);    // epilogue alias (p2 buf0, free)

    const int tid = threadIdx.x, w = tid >> 6, lane = tid & 63;
    const int l15 = lane & 15, quad = lane >> 4;
    const int m0 = blockIdx.x * 32;
    const int rin8 = lane >> 3, c8 = lane & 7;
    const int swz8 = (c8 ^ rin8) << 3;

    // ---------------- phase 1: H = relu(X*W1^T + b1), 32 x 1024 ----------
    f32x4 acc1[2][8];
#pragma unroll
    for (int mi = 0; mi < 2; mi++)
#pragma unroll
        for (int j = 0; j < 8; j++) acc1[mi][j] = (f32x4){0.f, 0.f, 0.f, 0.f};

#pragma unroll
    for (int j = 0; j < 4; j++) {           // X panel (32 x 512)
        int row = j * 8 + w;
        gll16(X + (size_t)(m0 + row) * HDIM + ((lane ^ (row & 7)) << 3),
              Apan + row * 1024);
    }
#define F1ISS(c)                                                              \
    do {                                                                      \
        int rg_ = (c) & 3, kst_ = (c) >> 2;                                   \
        char* bp_ = ring + ((c) % 3) * 32768;                                 \
        _Pragma("unroll")                                                     \
        for (int j_ = 0; j_ < 4; j_++) {                                      \
            int seg_ = j_ * 8 + w;                                            \
            int ric_ = seg_ * 8 + rin8;                                       \
            gll16(W1 + (size_t)(rg_ * 256 + ric_) * HDIM + kst_ * 64 + swz8,  \
                  bp_ + seg_ * 1024);                                         \
        }                                                                     \
    } while (0)
#define F2ISS(c)                                                              \
    do {                                                                      \
        int rg_ = (c) & 1, kst_ = (c) >> 1;                                   \
        char* bp_ = W2b + ((c) & 1) * 32768;                                  \
        _Pragma("unroll")                                                     \
        for (int j_ = 0; j_ < 4; j_++) {                                      \
            int seg_ = j_ * 8 + w;                                            \
            int ric_ = seg_ * 8 + rin8;                                       \
            gll16(W2 + (size_t)(rg_ * 256 + ric_) * FF + kst_ * 64 + swz8,    \
                  bp_ + seg_ * 1024);                                         \
        }                                                                     \
    } while (0)

    F1ISS(0); F1ISS(1);
    VM4();
    BAR(); SCHED0();

    for (int c = 0; c < 32; c++) {          // 8 ksteps x 4 row-groups
        if (c + 2 < 32) F1ISS(c + 2);
        {
            int kst = c >> 2, rg = c & 3;
            const char* bp = ring + (c % 3) * 32768;
#pragma unroll
            for (int ks = 0; ks < 2; ks++) {
                short8 af[2];
#pragma unroll
                for (int mi = 0; mi < 2; mi++) {
                    int ar = mi * 16 + l15;
                    af[mi] = *(const short8*)(Apan + ar * 1024 +
                        (((kst * 8 + ks * 4 + quad) ^ (ar & 7)) << 4));
                }
#pragma unroll
                for (int ni = 0; ni < 2; ni++) {
                    int rr = w * 32 + ni * 16 + l15;
                    short8 wf = *(const short8*)(bp + rr * 128 +
                        (((ks * 4 + quad) ^ (rr & 7)) << 4));
#pragma unroll
                    for (int mi = 0; mi < 2; mi++)
                        acc1[mi][rg * 2 + ni] = __builtin_amdgcn_mfma_f32_16x16x32_bf16(
                            wf, af[mi], acc1[mi][rg * 2 + ni], 0, 0, 0);
                }
            }
        }
        if (c + 1 < 32) {
            if (c + 2 < 32) VM4(); else VM0();
            BAR(); SCHED0();
        }
    }
    __syncthreads();        // all waves done with Apan + ring

    // ---- transition: prefetch W2 chunks 0,1; park H in LDS ---------------
    F2ISS(0); F2ISS(1);
    // H write: row = mi*16+l15 (2048B rows), n = (j>>1)*256+w*32+(j&1)*16+quad*4
#pragma unroll
    for (int mi = 0; mi < 2; mi++)
#pragma unroll
        for (int j = 0; j < 8; j++) {
            int n = (j >> 1) * 256 + w * 32 + (j & 1) * 16 + quad * 4;
            f32x4 bz = *(const f32x4*)(b1 + n);
            short4v pk;
#pragma unroll
            for (int r = 0; r < 4; r++)
                pk[r] = f2bf(fmaxf(acc1[mi][j][r] + bz[r], 0.f));
            int row = mi * 16 + l15;
            int u = n >> 3;
            *(short4v*)(Hs + row * 2048 + ((u ^ (row & 7)) << 4) + (quad & 1) * 8) = pk;
        }
    LGKM0();                // own H stores drained
    VM4();                  // W2 chunk 0 resident (chunk 1 flying)
    BAR(); SCHED0();

    // ---------------- phase 2: Y = LN(H*W2^T + b2 + X) --------------------
    f32x4 acc2[2][4];
#pragma unroll
    for (int mi = 0; mi < 2; mi++)
#pragma unroll
        for (int j = 0; j < 4; j++) acc2[mi][j] = (f32x4){0.f, 0.f, 0.f, 0.f};

    for (int c = 0; c < 32; c++) {          // 16 ksteps x 2 row-groups
        {
            int kst = c >> 1, rg = c & 1;
            const char* bp = W2b + (c & 1) * 32768;
#pragma unroll
            for (int ks = 0; ks < 2; ks++) {
                short8 af[2];
#pragma unroll
                for (int mi = 0; mi < 2; mi++) {
                    int ar = mi * 16 + l15;
                    af[mi] = *(const short8*)(Hs + ar * 2048 +
                        (((kst * 8 + ks * 4 + quad) ^ (ar & 7)) << 4));
                }
#pragma unroll
                for (int ni = 0; ni < 2; ni++) {
                    int rr = w * 32 + ni * 16 + l15;
                    short8 wf = *(const short8*)(bp + rr * 128 +
                        (((ks * 4 + quad) ^ (rr & 7)) << 4));
#pragma unroll
                    for (int mi = 0; mi < 2; mi++)
                        acc2[mi][rg * 2 + ni] = __builtin_amdgcn_mfma_f32_16x16x32_bf16(
                            wf, af[mi], acc2[mi][rg * 2 + ni], 0, 0, 0);
                }
            }
        }
        if (c + 1 < 32) {
            BAR(); SCHED0();                // all done reading buf[c&1]
            if (c + 2 < 32) { F2ISS(c + 2); VM4(); } else VM0();
            BAR(); SCHED0();                // chunk c+1 resident for all
        }
    }
#undef F1ISS
#undef F2ISS

    // ---- epilogue: bias + residual(X, global) -> LN -> store -------------
    float sum[2] = {0.f, 0.f}, sq[2] = {0.f, 0.f};
#pragma unroll
    for (int mi = 0; mi < 2; mi++)
#pragma unroll
        for (int j = 0; j < 4; j++) {
            int nb = (j >> 1) * 256 + w * 32 + (j & 1) * 16 + quad * 4;
            f32x4 bz = *(const f32x4*)(b2 + nb);
            short4v rv = *(const short4v*)(X + (size_t)(m0 + mi * 16 + l15) * HDIM + nb);
            f32x4 v;
#pragma unroll
            for (int r = 0; r < 4; r++) v[r] = acc2[mi][j][r] + bz[r] + bf2f(rv[r]);
            acc2[mi][j] = v;
            sum[mi] += v[0] + v[1] + v[2] + v[3];
            sq[mi]  += v[0] * v[0] + v[1] * v[1] + v[2] * v[2] + v[3] * v[3];
        }
#pragma unroll
    for (int mi = 0; mi < 2; mi++) {
        sum[mi] += __shfl_xor(sum[mi], 16); sum[mi] += __shfl_xor(sum[mi], 32);
        sq[mi]  += __shfl_xor(sq[mi], 16);  sq[mi]  += __shfl_xor(sq[mi], 32);
    }
    if (quad == 0) {
#pragma unroll
        for (int mi = 0; mi < 2; mi++) {
            red[(mi * 16 + l15) * 8 + w]       = sum[mi];
            red[256 + (mi * 16 + l15) * 8 + w] = sq[mi];
        }
    }
    __syncthreads();
    float mean[2], inv[2];
#pragma unroll
    for (int mi = 0; mi < 2; mi++) {
        f32x4 s0 = *(const f32x4*)(red + (mi * 16 + l15) * 8);
        f32x4 s1 = *(const f32x4*)(red + (mi * 16 + l15) * 8 + 4);
        f32x4 q0 = *(const f32x4*)(red + 256 + (mi * 16 + l15) * 8);
        f32x4 q1 = *(const f32x4*)(red + 256 + (mi * 16 + l15) * 8 + 4);
        float st = s0[0] + s0[1] + s0[2] + s0[3] + s1[0] + s1[1] + s1[2] + s1[3];
        float qt = q0[0] + q0[1] + q0[2] + q0[3] + q1[0] + q1[1] + q1[2] + q1[3];
        float mn = st * (1.f / HDIM);
        float vr = qt * (1.f / HDIM) - mn * mn;
        mean[mi] = mn;
        inv[mi]  = rsqrtf(vr + EPS);
    }
#pragma unroll
    for (int mi = 0; mi < 2; mi++)
#pragma unroll
        for (int j = 0; j < 4; j++) {
            int nb = (j >> 1) * 256 + w * 32 + (j & 1) * 16 + quad * 4;
            f32x4 gv = *(const f32x4*)(g + nb);
            f32x4 bv = *(const f32x4*)(bta + nb);
            short4v pk;
#pragma unroll
            for (int r = 0; r < 4; r++)
                pk[r] = f2bf((acc2[mi][j][r] - mean[mi]) * inv[mi] * gv[r] + bv[r]);
            *(short4v*)(Y + (size_t)(m0 + mi * 16 + l15) * HDIM + nb) = pk;
        }
}

// ---------------------------------------------------------------------------
// MFMA flash attention. Key-permuted K staging makes S^T's C-layout directly a
// K=32 B-frag for PV (16x16x32, full-rate, zero shuffles). K staged from
// head-major Kt (B,NH,S,HD): 128B-contiguous key rows -> 8 cache lines per
// gll16. 128-key tile per barrier pair.
#define EXP2SC 0.18033688011112042f   /* 0.125 * log2(e) */
__global__ __launch_bounds__(256, 4)
void attn_mfma(const short* __restrict__ qkv, const short* __restrict__ ktr,
               const short* __restrict__ vt,
               const u64* __restrict__ maskS, const u64* __restrict__ maskL,
               const u64* __restrict__ maskG, short* __restrict__ out) {
    const int tid = threadIdx.x;
    const int w = tid >> 6, lane = tid & 63, l15 = lane & 15, quad = lane >> 4;
    const int p = blockIdx.x;
    const int g_ = (p & 7) + 8 * (p >> 7);          // (b,h) group, XCD-swizzled
    const int qt = (p >> 3) & 15;
    const int b = g_ >> 3, h = g_ & 7;
    const int q = qt * 64 + w * 16 + l15;

    __shared__ __align__(16) short Ks[128 * 64];    // 128 keys (permuted) x 64 d
    __shared__ __align__(16) short Vs[128 * 64];    // 2 halves: 64 d x 64 keys

    short8 qf[2];
    {
        const short* qrow = qkv + ((size_t)(b * SEQ + q) * 1536) + h * 64;
#pragma unroll
        for (int ks = 0; ks < 2; ks++)
            qf[ks] = *(const short8*)(qrow + ks * 32 + quad * 8);
    }
    const u64* mrow = (h < 4) ? (maskS + ((size_t)b * SEQ + q) * 16)
                   : (h < 6) ? (maskL + ((size_t)b * SEQ + q) * 16)
                   :           (maskG + (size_t)b * 16);

    f32x4 of[4];
#pragma unroll
    for (int mt = 0; mt < 4; mt++) of[mt] = (f32x4){0.f, 0.f, 0.f, 0.f};
    float ls0 = 0.f, ls1 = 0.f;

    const int r_in = lane >> 3, c8 = lane & 7;
    const int swz = (c8 ^ r_in) << 3;   // chunk-invariant staging swizzle
    const short* kbase = ktr + ((size_t)(b * NH + h) * SEQ) * HD + swz;
    const short* vp = vt + ((size_t)((b * NH + h) * HD) + r_in) * SEQ + swz;
    const int fsw = (l15 & 7);

    for (int kt = 0; kt < SEQ; kt += 128) {
#pragma unroll
        for (int rep = 0; rep < 4; rep++) {         // K: permuted rows
            int c = rep * 4 + w;
            int pr = c * 8 + r_in;                  // physical staged row
            int pt = pr & 63;
            int key = (pr & 64) | (pt & 32) | (((pt >> 2) & 3) << 3)
                    | (((pt >> 4) & 1) << 2) | (pt & 3);
            gll16(kbase + (size_t)(kt + key) * HD, (char*)Ks + c * 1024);
        }
#pragma unroll
        for (int rep = 0; rep < 4; rep++) {         // V: plain, 2 halves x 8
            int v = rep * 4 + w;
            gll16(vp + (size_t)((v & 7) * 8) * SEQ + kt + (v >> 3) * 64,
                  (char*)Vs + v * 1024);
        }
        __syncthreads();

#pragma unroll
        for (int t = 0; t < 2; t++) {
            // S^T sub-tile (64 permuted keys x 16 q)
            f32x4 sa[4];
#pragma unroll
            for (int g = 0; g < 4; g++) sa[g] = (f32x4){0.f, 0.f, 0.f, 0.f};
#pragma unroll
            for (int ks = 0; ks < 2; ks++) {
                const int dblk = ks * 4 + quad;
#pragma unroll
                for (int g = 0; g < 4; g++) {
                    int row = t * 64 + g * 16 + l15;
                    short8 kf = *(const short8*)((const char*)Ks + row * 128 + ((dblk ^ fsw) << 4));
                    sa[g] = __builtin_amdgcn_mfma_f32_16x16x32_bf16(kf, qf[ks], sa[g], 0, 0, 0);
                }
            }
            // masked softmax numerator (max-free); logical bitpos for slot
            // (g,quad,r) is quad*8 + (g>>1)*32 + (g&1)*4 + r
            u64 mw = mrow[(kt >> 6) + t];
            if ((q >> 6) == (kt >> 6) + t) mw |= 1ull << (q & 63);
            u64 mq2 = mw >> (quad * 8);
            unsigned mlo = (unsigned)mq2, mhi = (unsigned)(mq2 >> 32);
            float pv[4][4];
#pragma unroll
            for (int g = 0; g < 4; g++) {
                unsigned mg = ((g & 2) ? mhi : mlo) >> ((g & 1) * 4);
#pragma unroll
                for (int r = 0; r < 4; r++) {
                    float e = fexp2(sa[g][r] * EXP2SC);
                    e = ((mg >> r) & 1u) ? e : 0.f;
                    pv[g][r] = e;
                    if (g & 1) ls1 += e; else ls0 += e;
                }
            }
            // pack C reg-pairs directly into K=32 B-frags (no shuffles)
            short8 pfrag[2];
#pragma unroll
            for (int g32 = 0; g32 < 2; g32++) {
                uint4v pk;
                pk[0] = __builtin_amdgcn_perm(__float_as_uint(pv[2 * g32][1]),
                                              __float_as_uint(pv[2 * g32][0]), 0x07060302u);
                pk[1] = __builtin_amdgcn_perm(__float_as_uint(pv[2 * g32][3]),
                                              __float_as_uint(pv[2 * g32][2]), 0x07060302u);
                pk[2] = __builtin_amdgcn_perm(__float_as_uint(pv[2 * g32 + 1][1]),
                                              __float_as_uint(pv[2 * g32 + 1][0]), 0x07060302u);
                pk[3] = __builtin_amdgcn_perm(__float_as_uint(pv[2 * g32 + 1][3]),
                                              __float_as_uint(pv[2 * g32 + 1][2]), 0x07060302u);
                pfrag[g32] = __builtin_bit_cast(short8, pk);
            }
            // O^T += V^T . P^T  (16x16x32, 8 MFMAs per sub-tile)
#pragma unroll
            for (int g32 = 0; g32 < 2; g32++) {
                const int u = g32 * 4 + quad;
#pragma unroll
                for (int mt = 0; mt < 4; mt++) {
                    int row = mt * 16 + l15;
                    short8 vf = *(const short8*)((const char*)Vs + t * 8192 + row * 128 + ((u ^ fsw) << 4));
                    of[mt] = __builtin_amdgcn_mfma_f32_16x16x32_bf16(vf, pfrag[g32], of[mt], 0, 0, 0);
                }
            }
        }
        __syncthreads();
    }
    float lsum = ls0 + ls1;
    lsum += __shfl_xor(lsum, 16);
    lsum += __shfl_xor(lsum, 32);
    float inv = 1.f / lsum;              // diagonal always allowed -> lsum > 0
#pragma unroll
    for (int mt = 0; mt < 4; mt++) {
        short4v pk;
#pragma unroll
        for (int r = 0; r < 4; r++) pk[r] = f2bf(of[mt][r] * inv);
        *(short4v*)(out + ((size_t)(b * SEQ + q) * HDIM) + h * 64 + mt * 16 + quad * 4) = pk;
    }
}

// ---------------------------------------------------------------------------
__global__ __launch_bounds__(256) void final_bn(const short* __restrict__ X,
                                                const float* __restrict__ g,
                                                const float* __restrict__ bb,
                                                float* __restrict__ out) {
    int h = blockIdx.x * 256 + threadIdx.x;
    if (h >= HDIM) return;
    float vals[BATCH];
    float m = 0.f;
#pragma unroll
    for (int b = 0; b < BATCH; b++) {
        vals[b] = bf2f(X[(size_t)b * SEQ * HDIM + h]);
        m += vals[b];
    }
    m *= (1.f / BATCH);
    float v = 0.f;
#pragma unroll
    for (int b = 0; b < BATCH; b++) { float d = vals[b] - m; v += d * d; }
    v *= (1.f / BATCH);
    float inv = rsqrtf(v + EPS);
#pragma unroll
    for (int b = 0; b < BATCH; b++)
        out[b * HDIM + h] = (vals[b] - m) * inv * g[h] + bb[h];
}

// ---------------------------------------------------------------------------
extern "C" void kernel_launch(void* const* d_in, const int* in_sizes, int n_in,
                              void* d_out, int out_size, void* d_ws, size_t ws_size,
                              hipStream_t stream) {
    const float* nodes      = (const float*)d_in[0];
    const int*   dist       = (const int*)  d_in[1];
    const float* dense_w    = (const float*)d_in[2];
    const float* dense_b    = (const float*)d_in[3];
    const float* dense_ln_g = (const float*)d_in[4];
    const float* dense_ln_b = (const float*)d_in[5];
    const float* qkv_w      = (const float*)d_in[6];
    const float* qkv_b      = (const float*)d_in[7];
    const float* out_w      = (const float*)d_in[8];
    const float* out_b      = (const float*)d_in[9];
    const float* ln1_g      = (const float*)d_in[10];
    const float* ln1_b      = (const float*)d_in[11];
    const float* ffn_w1     = (const float*)d_in[12];
    const float* ffn_b1     = (const float*)d_in[13];
    const float* ffn_w2     = (const float*)d_in[14];
    const float* ffn_b2     = (const float*)d_in[15];
    const float* ln2_g      = (const float*)d_in[16];
    const float* ln2_b      = (const float*)d_in[17];
    const float* bn_g       = (const float*)d_in[18];
    const float* bn_b       = (const float*)d_in[19];
    float* out = (float*)d_out;

    const int M = BATCH * SEQ;                         // 8192
    const size_t MB = 1024 * 1024;
    char* ws = (char*)d_ws;
    short* Wd   = (short*)(ws + 0 * MB);
    short* Wqkv = (short*)(ws + 1 * MB);
    short* Wo   = (short*)(ws + 9 * MB);
    short* W1   = (short*)(ws + 13 * MB);
    short* W2   = (short*)(ws + 18 * MB);
    u64*   mS   = (u64*)(ws + 23 * MB);
    u64*   mL   = (u64*)(ws + 24 * MB);
    u64*   mG   = (u64*)(ws + 25 * MB);
    short* X    = (short*)(ws + 26 * MB);
    short* QKV  = (short*)(ws + 34 * MB);
    short* Vt   = (short*)(ws + 58 * MB);
    short* AT   = (short*)(ws + 66 * MB);
    short* Kt   = (short*)(ws + 74 * MB);
    short* XT   = QKV;

    prep_all<<<PREP_W + PREP_N + BATCH * SEQ, 256, 0, stream>>>(
        dense_w, Wd, qkv_w, Wqkv, out_w, Wo, ffn_w1, W1, ffn_w2, W2,
        nodes, XT, dist, mS, mL, mG);

    // dense projection + dense LN, fused
    gemm_ln<IDIM, false><<<M / 32, 512, 0, stream>>>(
        XT, Wd, dense_b, nullptr, dense_ln_g, dense_ln_b, X);

    for (int l = 0; l < LAYERS; l++) {
        const short* wqkv = Wqkv + (size_t)l * 3 * HDIM * HDIM;
        const float* bqkv = qkv_b + (size_t)l * 3 * HDIM;
        const short* wo   = Wo + (size_t)l * HDIM * HDIM;
        const float* bo   = out_b + (size_t)l * HDIM;
        const short* w1   = W1 + (size_t)l * FF * HDIM;
        const float* b1   = ffn_b1 + (size_t)l * FF;
        const short* w2   = W2 + (size_t)l * HDIM * FF;
        const float* b2   = ffn_b2 + (size_t)l * HDIM;

        gemm_bf16<128, 128><<<dim3(3 * HDIM / 128, M / 128), 256, 0, stream>>>(
            X, wqkv, bqkv, QKV, Vt, Kt, M, 3 * HDIM, HDIM, 0);
        attn_mfma<<<1024, 256, 0, stream>>>(QKV, Kt, Vt, mS, mL, mG, AT);
        // attn out projection + residual + LN1, fused
        gemm_ln<HDIM, true><<<M / 32, 512, 0, stream>>>(
            AT, wo, bo, X, ln1_g + l * HDIM, ln1_b + l * HDIM, X);
        // FFN up + relu + down + residual + LN2, fully fused (no F1 buffer)
        fused_ffn<<<M / 32, 512, 0, stream>>>(
            X, w1, b1, w2, b2, ln2_g + l * HDIM, ln2_b + l * HDIM, X);
    }
    final_bn<<<(HDIM + 255) / 256, 256, 0, stream>>>(X, bn_g, bn_b, out);
}

// Round 10
// 558.034 us; speedup vs baseline: 1.0619x; 1.0042x over previous
//
#include <hip/hip_runtime.h>
#include <hip/hip_bf16.h>
#include <math.h>

#define LAYERS 4
#define IDIM 256
#define HDIM 512
#define NH 8
#define HD 64
#define FF 1024
#define SEQ 1024
#define BATCH 8
#define EPS 1e-5f

typedef __attribute__((ext_vector_type(8))) short short8;
typedef __attribute__((ext_vector_type(4))) short short4v;
typedef __attribute__((ext_vector_type(4))) float f32x4;
typedef __attribute__((ext_vector_type(4))) int int4v;
typedef __attribute__((ext_vector_type(4))) unsigned int uint4v;
typedef unsigned long long u64;

// fp32 -> bf16 (RNE) on raw bits
__device__ __forceinline__ short f2bf(float f) {
    unsigned u = __float_as_uint(f);
    u = (u + 0x7FFFu + ((u >> 16) & 1u)) >> 16;
    return (short)u;
}
__device__ __forceinline__ float bf2f(short s) {
    return __uint_as_float(((unsigned)(unsigned short)s) << 16);
}
__device__ __forceinline__ void gll16(const void* g, void* l) {
    __builtin_amdgcn_global_load_lds(
        (const __attribute__((address_space(1))) unsigned int*)g,
        (__attribute__((address_space(3))) unsigned int*)l, 16, 0, 0);
}
// raw v_exp_f32 (2^x); exp2f may expand to a libm sequence
__device__ __forceinline__ float fexp2(float x) {
#if __has_builtin(__builtin_amdgcn_exp2f)
    return __builtin_amdgcn_exp2f(x);
#else
    return exp2f(x);
#endif
}

#define BAR() __builtin_amdgcn_s_barrier()
#define SCHED0() __builtin_amdgcn_sched_barrier(0)
#define VM4() asm volatile("s_waitcnt vmcnt(4)" ::: "memory")
#define VM2() asm volatile("s_waitcnt vmcnt(2)" ::: "memory")
#define VM0() asm volatile("s_waitcnt vmcnt(0)" ::: "memory")
#define LGKM0() asm volatile("s_waitcnt lgkmcnt(0)" ::: "memory")

// ---------------------------------------------------------------------------
// merged prep: weight cvt (8320 blocks) + nodes transpose (2048 blocks) +
// ballot-based mask build (8192 blocks, one per (b,q), coalesced dist reads).
#define CVT_P0 131072u
#define CVT_P1 3276800u
#define CVT_P2 4325376u
#define CVT_P3 6422528u
#define CVT_TOT 8519680u
#define PREP_W 8320
#define PREP_N 2048
__global__ __launch_bounds__(256) void prep_all(
    const float* __restrict__ s0, short* __restrict__ d0,
    const float* __restrict__ s1, short* __restrict__ d1,
    const float* __restrict__ s2, short* __restrict__ d2,
    const float* __restrict__ s3, short* __restrict__ d3,
    const float* __restrict__ s4, short* __restrict__ d4,
    const float* __restrict__ nodes, short* __restrict__ xt,
    const int* __restrict__ dist, u64* __restrict__ mS,
    u64* __restrict__ mL, u64* __restrict__ mG) {
    int blk = blockIdx.x;
    if (blk < PREP_W) {                     // weight fp32->bf16
        size_t i = ((size_t)blk * 256 + threadIdx.x) * 4;
        const float* s; short* d; size_t off;
        if (i < CVT_P0)      { s = s0; d = d0; off = i; }
        else if (i < CVT_P1) { s = s1; d = d1; off = i - CVT_P0; }
        else if (i < CVT_P2) { s = s2; d = d2; off = i - CVT_P1; }
        else if (i < CVT_P3) { s = s3; d = d3; off = i - CVT_P2; }
        else                 { s = s4; d = d4; off = i - CVT_P3; }
        f32x4 f = *(const f32x4*)(s + off);
        short4v o = {f2bf(f[0]), f2bf(f[1]), f2bf(f[2]), f2bf(f[3])};
        *(short4v*)(d + off) = o;
    } else if (blk < PREP_W + PREP_N) {     // nodes (S,B,I) -> (B*S,I) bf16
        size_t idx = ((size_t)(blk - PREP_W) * 256 + threadIdx.x) * 4;
        int i  = idx & (IDIM - 1);
        int sb = idx >> 8;
        int b  = sb & (BATCH - 1);
        int s  = sb >> 3;
        f32x4 f = *(const f32x4*)(nodes + idx);
        short4v o = {f2bf(f[0]), f2bf(f[1]), f2bf(f[2]), f2bf(f[3])};
        *(short4v*)(xt + ((size_t)b * SEQ + s) * IDIM + i) = o;
    } else {                                // ballot mask build, 1 blk per (b,q)
        int blk2 = blk - (PREP_W + PREP_N);
        int b = blk2 >> 10, q = blk2 & 1023;
        int wv = threadIdx.x >> 6, lane = threadIdx.x & 63;
        const int* dp = dist + ((size_t)b * SEQ + q) * SEQ;
        size_t mbase = ((size_t)b * SEQ + q) * 16;
#pragma unroll
        for (int it = 0; it < 4; it++) {
            int w64 = it * 4 + wv;
            int d = dp[w64 * 64 + lane];
            u64 bs = __ballot(d == 1);
            u64 bl = __ballot(d >= 1);
            if (lane == 0) {
                mS[mbase + w64] = bs;
                mL[mbase + w64] = bl;
                if (q == 0) mG[b * 16 + w64] = bl;
            }
        }
    }
}

// ---------------------------------------------------------------------------
// bf16 MFMA GEMM (16x16x32). BM x 128 tile. Used ONLY for QKV now; BK=128
// halves the barrier-drain count (4 K-steps at K=512, 64 MFMA per drain) —
// R8-verified ~11us wall win. V-blocks (n0>=1024) -> transposed Vt
// (B,NH,HD,S); K-blocks (512<=n0<1024) -> head-major Kt (B,NH,S,HD);
// Q-blocks -> C. Bias folded everywhere.
template<int BM, int BK>
__global__ __launch_bounds__(256, 2)
void gemm_bf16(const short* __restrict__ A, const short* __restrict__ W,
               const float* __restrict__ bias, short* __restrict__ C,
               short* __restrict__ vt, short* __restrict__ ktr,
               int M, int N, int K, int relu) {
    constexpr int UPR = BK / 8;        // 16B units per row
    constexpr int RPC = 512 / BK;      // rows per 1KB staging chunk
    __shared__ __align__(16) short As[BM * BK];
    __shared__ __align__(16) short Ws[128 * BK];
    const int tid = threadIdx.x;
    const int w = tid >> 6, lane = tid & 63;
    const int l15 = lane & 15, quad = lane >> 4;
    const int m0 = blockIdx.y * BM, n0 = blockIdx.x * 128;

    constexpr int NI = (BM == 128) ? 4 : 2;
    const int wm = (BM == 128) ? (w >> 1) * 64 : 0;
    const int wn = (BM == 128) ? (w & 1) * 64 : w * 32;

    f32x4 acc[4][NI];
#pragma unroll
    for (int mi = 0; mi < 4; mi++)
#pragma unroll
        for (int ni = 0; ni < NI; ni++) acc[mi][ni] = (f32x4){0.f, 0.f, 0.f, 0.f};

    const int r_in = (BK == 64) ? (lane >> 3) : (lane >> 4);
    const int c8   = lane & (UPR - 1);

    for (int k0 = 0; k0 < K; k0 += BK) {
#pragma unroll
        for (int rep = 0; rep < BM * BK / 2048; rep++) {
            int chunk = rep * 4 + w;
            int row = chunk * RPC + r_in;
            const short* src = A + (size_t)(m0 + row) * K + k0 + ((c8 ^ (row & (UPR - 1))) << 3);
            gll16(src, (char*)As + chunk * 1024);
        }
#pragma unroll
        for (int rep = 0; rep < 128 * BK / 2048; rep++) {
            int chunk = rep * 4 + w;
            int row = chunk * RPC + r_in;
            const short* src = W + (size_t)(n0 + row) * K + k0 + ((c8 ^ (row & (UPR - 1))) << 3);
            gll16(src, (char*)Ws + chunk * 1024);
        }
        __syncthreads();
#pragma unroll
        for (int ks = 0; ks < BK / 32; ks++) {
            short8 af[4], wf[NI];
            const int dblk = ks * 4 + quad;
#pragma unroll
            for (int mi = 0; mi < 4; mi++) {
                int row = wm + mi * 16 + l15;
                af[mi] = *(const short8*)((const char*)As + row * (BK * 2) + ((dblk ^ (row & (UPR - 1))) << 4));
            }
#pragma unroll
            for (int ni = 0; ni < NI; ni++) {
                int row = wn + ni * 16 + l15;
                wf[ni] = *(const short8*)((const char*)Ws + row * (BK * 2) + ((dblk ^ (row & (UPR - 1))) << 4));
            }
#pragma unroll
            for (int mi = 0; mi < 4; mi++)
#pragma unroll
                for (int ni = 0; ni < NI; ni++)
                    acc[mi][ni] = __builtin_amdgcn_mfma_f32_16x16x32_bf16(
                        af[mi], wf[ni], acc[mi][ni], 0, 0, 0);
        }
        __syncthreads();
    }
    if (vt && n0 >= 1024) {
        // V-projection epilogue: plain transpose into Vt (B,NH,HD,S)
#pragma unroll
        for (int ni = 0; ni < NI; ni++) {
            int n = n0 + wn + ni * 16 + l15;
            int d = n - 1024, h = d >> 6, dd = d & 63;
            float bz = bias[n];
#pragma unroll
            for (int mi = 0; mi < 4; mi++) {
                int mbase = m0 + wm + mi * 16 + quad * 4;   // 4 consecutive s
                int b = mbase >> 10, s = mbase & 1023;
                size_t off = ((size_t)(b * NH + h) * HD + dd) * SEQ + s;
                short4v pk;
#pragma unroll
                for (int r = 0; r < 4; r++) pk[r] = f2bf(acc[mi][ni][r] + bz);
                *(short4v*)(vt + off) = pk;
            }
        }
    } else if (ktr && n0 >= 512) {
        // K-projection epilogue: head-major Kt (B,NH,S,HD), bias folded
#pragma unroll
        for (int ni = 0; ni < NI; ni++) {
            int n = n0 + wn + ni * 16 + l15;
            int d = n - 512, h = d >> 6, dd = d & 63;
            float bz = bias[n];
#pragma unroll
            for (int mi = 0; mi < 4; mi++) {
                int mbase = m0 + wm + mi * 16 + quad * 4;   // 4 consecutive s
                int b = mbase >> 10, s = mbase & 1023;
                size_t base = ((size_t)(b * NH + h) * SEQ + s) * HD + dd;
#pragma unroll
                for (int r = 0; r < 4; r++)
                    ktr[base + (size_t)r * HD] = f2bf(acc[mi][ni][r] + bz);
            }
        }
    } else {
#pragma unroll
        for (int ni = 0; ni < NI; ni++) {
            int n = n0 + wn + ni * 16 + l15;
            float bz = bias[n];
#pragma unroll
            for (int mi = 0; mi < 4; mi++) {
#pragma unroll
                for (int r = 0; r < 4; r++) {
                    int m = m0 + wm + mi * 16 + quad * 4 + r;
                    float v = acc[mi][ni][r] + bz;
                    if (relu) v = fmaxf(v, 0.f);
                    C[(size_t)m * N + n] = f2bf(v);
                }
            }
        }
    }
}

// ---------------------------------------------------------------------------
// Fused full-row GEMM + bias + (residual) + LayerNorm, 3-buf counted-vmcnt
// W stream. BM=32 rows x 512 cols, 512 thr. A panel staged ONCE. W streamed
// in 32KB chunks (256 rows x 64 k, 128B rows + XOR-8 = conflict-free), ring
// of 3 buffers, ONE barrier per chunk, vmcnt(4) steady state (never 0).
// 8 MFMA + 8 ds_read_b128 per barrier. Swapped MFMA operands -> acc
// n-contiguous; fused LN epilogue.
template<int K, bool RES>
__global__ __launch_bounds__(512, 1)
void gemm_ln(const short* __restrict__ A, const short* __restrict__ W,
             const float* __restrict__ bias, const short* __restrict__ resid,
             const float* __restrict__ g, const float* __restrict__ bta,
             short* __restrict__ Y) {
    constexpr int NCH = K / 32;             // (K/64 ksteps) x 2 row-groups
    __shared__ __align__(16) char smem[K * 64 + 98304];
    char* Apan = smem;                      // 32 rows x K (16/32 KB)
    char* ring = smem + K * 64;             // 3 x 32KB
    float* red = (float*)smem;              // epilogue alias

    const int tid = threadIdx.x, w = tid >> 6, lane = tid & 63;
    const int l15 = lane & 15, quad = lane >> 4;
    const int m0 = blockIdx.x * 32;
    const int rin8 = lane >> 3, c8 = lane & 7;
    const int swz8 = (c8 ^ rin8) << 3;      // staging source swizzle (shorts)

    f32x4 acc[2][4];
#pragma unroll
    for (int mi = 0; mi < 2; mi++)
#pragma unroll
        for (int j = 0; j < 4; j++) acc[mi][j] = (f32x4){0.f, 0.f, 0.f, 0.f};

    // ---- A panel stage (once) ----
    if constexpr (K == 512) {
#pragma unroll
        for (int j = 0; j < 4; j++) {
            int row = j * 8 + w;
            gll16(A + (size_t)(m0 + row) * K + ((lane ^ (row & 7)) << 3),
                  Apan + row * 1024);
        }
    } else {  // K == 256: 2 rows per 1KB segment
#pragma unroll
        for (int j = 0; j < 2; j++) {
            int seg = j * 8 + w;
            int row = seg * 2 + (lane >> 5);
            gll16(A + (size_t)(m0 + row) * K + (((lane & 31) ^ (row & 7)) << 3),
                  Apan + seg * 1024);
        }
    }
#define GISS(c)                                                               \
    do {                                                                      \
        int rg_ = (c) & 1, kst_ = (c) >> 1;                                   \
        char* bp_ = ring + ((c) % 3) * 32768;                                 \
        _Pragma("unroll")                                                     \
        for (int j_ = 0; j_ < 4; j_++) {                                      \
            int seg_ = j_ * 8 + w;                                            \
            int ric_ = seg_ * 8 + rin8;                                       \
            gll16(W + (size_t)(rg_ * 256 + ric_) * K + kst_ * 64 + swz8,      \
                  bp_ + seg_ * 1024);                                         \
        }                                                                     \
    } while (0)

    GISS(0); GISS(1);
    VM4();              // A + chunk0 resident (chunk1 in flight)
    BAR(); SCHED0();

    for (int c = 0; c < NCH; c++) {
        if (c + 2 < NCH) GISS(c + 2);       // into buffer freed 2 iters ago
        {
            int kst = c >> 1, rg = c & 1;
            const char* bp = ring + (c % 3) * 32768;
#pragma unroll
            for (int ks = 0; ks < 2; ks++) {
                short8 af[2];
#pragma unroll
                for (int mi = 0; mi < 2; mi++) {
                    int ar = mi * 16 + l15;
                    af[mi] = *(const short8*)(Apan + ar * (K * 2) +
                        (((kst * 8 + ks * 4 + quad) ^ (ar & 7)) << 4));
                }
#pragma unroll
                for (int ni = 0; ni < 2; ni++) {
                    int rr = w * 32 + ni * 16 + l15;
                    short8 wf = *(const short8*)(bp + rr * 128 +
                        (((ks * 4 + quad) ^ (rr & 7)) << 4));
#pragma unroll
                    for (int mi = 0; mi < 2; mi++)
                        acc[mi][rg * 2 + ni] = __builtin_amdgcn_mfma_f32_16x16x32_bf16(
                            wf, af[mi], acc[mi][rg * 2 + ni], 0, 0, 0);
                }
            }
        }
        if (c + 1 < NCH) {
            if (c + 2 < NCH) VM4(); else VM0();
            BAR(); SCHED0();
        }
    }
#undef GISS
    __syncthreads();    // Apan/ring reads done everywhere before red reuse

    // ---- fused epilogue: bias (+residual) -> row stats -> LN -> store ----
    // layout: m = m0 + mi*16 + l15, n = (j>>1)*256 + w*32 + (j&1)*16 + quad*4
    float sum[2] = {0.f, 0.f}, sq[2] = {0.f, 0.f};
#pragma unroll
    for (int mi = 0; mi < 2; mi++)
#pragma unroll
        for (int j = 0; j < 4; j++) {
            int nb = (j >> 1) * 256 + w * 32 + (j & 1) * 16 + quad * 4;
            f32x4 bz = *(const f32x4*)(bias + nb);
            f32x4 v;
            if (RES) {
                short4v rv = *(const short4v*)(resid + (size_t)(m0 + mi * 16 + l15) * HDIM + nb);
#pragma unroll
                for (int r = 0; r < 4; r++) v[r] = acc[mi][j][r] + bz[r] + bf2f(rv[r]);
            } else {
#pragma unroll
                for (int r = 0; r < 4; r++) v[r] = acc[mi][j][r] + bz[r];
            }
            acc[mi][j] = v;
            sum[mi] += v[0] + v[1] + v[2] + v[3];
            sq[mi]  += v[0] * v[0] + v[1] * v[1] + v[2] * v[2] + v[3] * v[3];
        }
#pragma unroll
    for (int mi = 0; mi < 2; mi++) {
        sum[mi] += __shfl_xor(sum[mi], 16); sum[mi] += __shfl_xor(sum[mi], 32);
        sq[mi]  += __shfl_xor(sq[mi], 16);  sq[mi]  += __shfl_xor(sq[mi], 32);
    }
    if (quad == 0) {
#pragma unroll
        for (int mi = 0; mi < 2; mi++) {
            red[(mi * 16 + l15) * 8 + w]       = sum[mi];
            red[256 + (mi * 16 + l15) * 8 + w] = sq[mi];
        }
    }
    __syncthreads();
    float mean[2], inv[2];
#pragma unroll
    for (int mi = 0; mi < 2; mi++) {
        f32x4 s0 = *(const f32x4*)(red + (mi * 16 + l15) * 8);
        f32x4 s1 = *(const f32x4*)(red + (mi * 16 + l15) * 8 + 4);
        f32x4 q0 = *(const f32x4*)(red + 256 + (mi * 16 + l15) * 8);
        f32x4 q1 = *(const f32x4*)(red + 256 + (mi * 16 + l15) * 8 + 4);
        float st = s0[0] + s0[1] + s0[2] + s0[3] + s1[0] + s1[1] + s1[2] + s1[3];
        float qt = q0[0] + q0[1] + q0[2] + q0[3] + q1[0] + q1[1] + q1[2] + q1[3];
        float mn = st * (1.f / HDIM);
        float vr = qt * (1.f / HDIM) - mn * mn;
        mean[mi] = mn;
        inv[mi]  = rsqrtf(vr + EPS);
    }
#pragma unroll
    for (int mi = 0; mi < 2; mi++)
#pragma unroll
        for (int j = 0; j < 4; j++) {
            int nb = (j >> 1) * 256 + w * 32 + (j & 1) * 16 + quad * 4;
            f32x4 gv = *(const f32x4*)(g + nb);
            f32x4 bv = *(const f32x4*)(bta + nb);
            short4v pk;
#pragma unroll
            for (int r = 0; r < 4; r++)
                pk[r] = f2bf((acc[mi][j][r] - mean[mi]) * inv[mi] * gv[r] + bv[r]);
            *(short4v*)(Y + (size_t)(m0 + mi * 16 + l15) * HDIM + nb) = pk;
        }
}

// ---------------------------------------------------------------------------
// Fused FFN: Y = LN(X + relu(X*W1^T + b1)*W2^T + b2). BM=32, 512 thr.
// Phase 1: W1 streamed in 32KB chunks (3-buf ring, 1 barrier/chunk, vmcnt(4)).
// H -> LDS (64KB). Phase 2: H consumed from LDS, W2 streamed (2-buf,
// 2-barrier — R5-proven; the R7 3-buf/160KB variant regressed ~32us wall).
// LDS 128KB: p1 = [X 32K | ring 96K]; p2 = [H 64K | 2x32K W2 bufs].
// Residual X re-read from global in the epilogue (H overwrites the X panel).
__global__ __launch_bounds__(512, 1)
void fused_ffn(const short* __restrict__ X, const short* __restrict__ W1,
               const float* __restrict__ b1, const short* __restrict__ W2,
               const float* __restrict__ b2, const float* __restrict__ g,
               const float* __restrict__ bta, short* __restrict__ Y) {
    __shared__ __align__(16) char smem[131072];
    char* Apan = smem;                      // 32KB: X panel (phase 1)
    char* ring = smem + 32768;              // 96KB: 3 x 32KB (phase 1)
    char* Hs   = smem;                      // 64KB: H (phase 2)
    char* W2b  = smem + 65536;              // 64KB: 2 x 32KB (phase 2)
    float* red = (float*)(smem + 65536);    // epilogue alias (p2 buf0, free)

    const int tid = threadIdx.x, w = tid >> 6, lane = tid & 63;
    const int l15 = lane & 15, quad = lane >> 4;
    const int m0 = blockIdx.x * 32;
    const int rin8 = lane >> 3, c8 = lane & 7;
    const int swz8 = (c8 ^ rin8) << 3;

    // ---------------- phase 1: H = relu(X*W1^T + b1), 32 x 1024 ----------
    f32x4 acc1[2][8];
#pragma unroll
    for (int mi = 0; mi < 2; mi++)
#pragma unroll
        for (int j = 0; j < 8; j++) acc1[mi][j] = (f32x4){0.f, 0.f, 0.f, 0.f};

#pragma unroll
    for (int j = 0; j < 4; j++) {           // X panel (32 x 512)
        int row = j * 8 + w;
        gll16(X + (size_t)(m0 + row) * HDIM + ((lane ^ (row & 7)) << 3),
              Apan + row * 1024);
    }
#define F1ISS(c)                                                              \
    do {                                                                      \
        int rg_ = (c) & 3, kst_ = (c) >> 2;                                   \
        char* bp_ = ring + ((c) % 3) * 32768;                                 \
        _Pragma("unroll")                                                     \
        for (int j_ = 0; j_ < 4; j_++) {                                      \
            int seg_ = j_ * 8 + w;                                            \
            int ric_ = seg_ * 8 + rin8;                                       \
            gll16(W1 + (size_t)(rg_ * 256 + ric_) * HDIM + kst_ * 64 + swz8,  \
                  bp_ + seg_ * 1024);                                         \
        }                                                                     \
    } while (0)
#define F2ISS(c)                                                              \
    do {                                                                      \
        int rg_ = (c) & 1, kst_ = (c) >> 1;                                   \
        char* bp_ = W2b + ((c) & 1) * 32768;                                  \
        _Pragma("unroll")                                                     \
        for (int j_ = 0; j_ < 4; j_++) {                                      \
            int seg_ = j_ * 8 + w;                                            \
            int ric_ = seg_ * 8 + rin8;                                       \
            gll16(W2 + (size_t)(rg_ * 256 + ric_) * FF + kst_ * 64 + swz8,    \
                  bp_ + seg_ * 1024);                                         \
        }                                                                     \
    } while (0)

    F1ISS(0); F1ISS(1);
    VM4();
    BAR(); SCHED0();

    for (int c = 0; c < 32; c++) {          // 8 ksteps x 4 row-groups
        if (c + 2 < 32) F1ISS(c + 2);
        {
            int kst = c >> 2, rg = c & 3;
            const char* bp = ring + (c % 3) * 32768;
#pragma unroll
            for (int ks = 0; ks < 2; ks++) {
                short8 af[2];
#pragma unroll
                for (int mi = 0; mi < 2; mi++) {
                    int ar = mi * 16 + l15;
                    af[mi] = *(const short8*)(Apan + ar * 1024 +
                        (((kst * 8 + ks * 4 + quad) ^ (ar & 7)) << 4));
                }
#pragma unroll
                for (int ni = 0; ni < 2; ni++) {
                    int rr = w * 32 + ni * 16 + l15;
                    short8 wf = *(const short8*)(bp + rr * 128 +
                        (((ks * 4 + quad) ^ (rr & 7)) << 4));
#pragma unroll
                    for (int mi = 0; mi < 2; mi++)
                        acc1[mi][rg * 2 + ni] = __builtin_amdgcn_mfma_f32_16x16x32_bf16(
                            wf, af[mi], acc1[mi][rg * 2 + ni], 0, 0, 0);
                }
            }
        }
        if (c + 1 < 32) {
            if (c + 2 < 32) VM4(); else VM0();
            BAR(); SCHED0();
        }
    }
    __syncthreads();        // all waves done with Apan + ring

    // ---- transition: prefetch W2 chunks 0,1; park H in LDS ---------------
    F2ISS(0); F2ISS(1);
    // H write: row = mi*16+l15 (2048B rows), n = (j>>1)*256+w*32+(j&1)*16+quad*4
#pragma unroll
    for (int mi = 0; mi < 2; mi++)
#pragma unroll
        for (int j = 0; j < 8; j++) {
            int n = (j >> 1) * 256 + w * 32 + (j & 1) * 16 + quad * 4;
            f32x4 bz = *(const f32x4*)(b1 + n);
            short4v pk;
#pragma unroll
            for (int r = 0; r < 4; r++)
                pk[r] = f2bf(fmaxf(acc1[mi][j][r] + bz[r], 0.f));
            int row = mi * 16 + l15;
            int u = n >> 3;
            *(short4v*)(Hs + row * 2048 + ((u ^ (row & 7)) << 4) + (quad & 1) * 8) = pk;
        }
    LGKM0();                // own H stores drained
    VM4();                  // W2 chunk 0 resident (chunk 1 flying)
    BAR(); SCHED0();

    // ---------------- phase 2: Y = LN(H*W2^T + b2 + X) --------------------
    f32x4 acc2[2][4];
#pragma unroll
    for (int mi = 0; mi < 2; mi++)
#pragma unroll
        for (int j = 0; j < 4; j++) acc2[mi][j] = (f32x4){0.f, 0.f, 0.f, 0.f};

    for (int c = 0; c < 32; c++) {          // 16 ksteps x 2 row-groups
        {
            int kst = c >> 1, rg = c & 1;
            const char* bp = W2b + (c & 1) * 32768;
#pragma unroll
            for (int ks = 0; ks < 2; ks++) {
                short8 af[2];
#pragma unroll
                for (int mi = 0; mi < 2; mi++) {
                    int ar = mi * 16 + l15;
                    af[mi] = *(const short8*)(Hs + ar * 2048 +
                        (((kst * 8 + ks * 4 + quad) ^ (ar & 7)) << 4));
                }
#pragma unroll
                for (int ni = 0; ni < 2; ni++) {
                    int rr = w * 32 + ni * 16 + l15;
                    short8 wf = *(const short8*)(bp + rr * 128 +
                        (((ks * 4 + quad) ^ (rr & 7)) << 4));
#pragma unroll
                    for (int mi = 0; mi < 2; mi++)
                        acc2[mi][rg * 2 + ni] = __builtin_amdgcn_mfma_f32_16x16x32_bf16(
                            wf, af[mi], acc2[mi][rg * 2 + ni], 0, 0, 0);
                }
            }
        }
        if (c + 1 < 32) {
            BAR(); SCHED0();                // all done reading buf[c&1]
            if (c + 2 < 32) { F2ISS(c + 2); VM4(); } else VM0();
            BAR(); SCHED0();                // chunk c+1 resident for all
        }
    }
#undef F1ISS
#undef F2ISS

    // ---- epilogue: bias + residual(X, global) -> LN -> store -------------
    float sum[2] = {0.f, 0.f}, sq[2] = {0.f, 0.f};
#pragma unroll
    for (int mi = 0; mi < 2; mi++)
#pragma unroll
        for (int j = 0; j < 4; j++) {
            int nb = (j >> 1) * 256 + w * 32 + (j & 1) * 16 + quad * 4;
            f32x4 bz = *(const f32x4*)(b2 + nb);
            short4v rv = *(const short4v*)(X + (size_t)(m0 + mi * 16 + l15) * HDIM + nb);
            f32x4 v;
#pragma unroll
            for (int r = 0; r < 4; r++) v[r] = acc2[mi][j][r] + bz[r] + bf2f(rv[r]);
            acc2[mi][j] = v;
            sum[mi] += v[0] + v[1] + v[2] + v[3];
            sq[mi]  += v[0] * v[0] + v[1] * v[1] + v[2] * v[2] + v[3] * v[3];
        }
#pragma unroll
    for (int mi = 0; mi < 2; mi++) {
        sum[mi] += __shfl_xor(sum[mi], 16); sum[mi] += __shfl_xor(sum[mi], 32);
        sq[mi]  += __shfl_xor(sq[mi], 16);  sq[mi]  += __shfl_xor(sq[mi], 32);
    }
    if (quad == 0) {
#pragma unroll
        for (int mi = 0; mi < 2; mi++) {
            red[(mi * 16 + l15) * 8 + w]       = sum[mi];
            red[256 + (mi * 16 + l15) * 8 + w] = sq[mi];
        }
    }
    __syncthreads();
    float mean[2], inv[2];
#pragma unroll
    for (int mi = 0; mi < 2; mi++) {
        f32x4 s0 = *(const f32x4*)(red + (mi * 16 + l15) * 8);
        f32x4 s1 = *(const f32x4*)(red + (mi * 16 + l15) * 8 + 4);
        f32x4 q0 = *(const f32x4*)(red + 256 + (mi * 16 + l15) * 8);
        f32x4 q1 = *(const f32x4*)(red + 256 + (mi * 16 + l15) * 8 + 4);
        float st = s0[0] + s0[1] + s0[2] + s0[3] + s1[0] + s1[1] + s1[2] + s1[3];
        float qt = q0[0] + q0[1] + q0[2] + q0[3] + q1[0] + q1[1] + q1[2] + q1[3];
        float mn = st * (1.f / HDIM);
        float vr = qt * (1.f / HDIM) - mn * mn;
        mean[mi] = mn;
        inv[mi]  = rsqrtf(vr + EPS);
    }
#pragma unroll
    for (int mi = 0; mi < 2; mi++)
#pragma unroll
        for (int j = 0; j < 4; j++) {
            int nb = (j >> 1) * 256 + w * 32 + (j & 1) * 16 + quad * 4;
            f32x4 gv = *(const f32x4*)(g + nb);
            f32x4 bv = *(const f32x4*)(bta + nb);
            short4v pk;
#pragma unroll
            for (int r = 0; r < 4; r++)
                pk[r] = f2bf((acc2[mi][j][r] - mean[mi]) * inv[mi] * gv[r] + bv[r]);
            *(short4v*)(Y + (size_t)(m0 + mi * 16 + l15) * HDIM + nb) = pk;
        }
}

// ---------------------------------------------------------------------------
// MFMA flash attention, 8-wave blocks: 2 q-tiles (waves 0-3 / 4-7) SHARE one
// K/V staging -> staging traffic + instruction count halve vs 4-wave blocks.
// Split-drain schedule per 128-key tile: issue K then V; vmcnt(2) -> K
// resident; QK^T + softmax + pack for BOTH sub-tiles (Ks-only, pfrags in
// regs); vmcnt(0) -> V arrived under compute; PV both sub-tiles; barrier.
// K staged from head-major Kt (B,NH,S,HD), key-permuted so S^T's C-layout is
// directly a K=32 B-frag for PV (zero shuffles).
#define EXP2SC 0.18033688011112042f   /* 0.125 * log2(e) */
__global__ __launch_bounds__(512, 4)
void attn_mfma(const short* __restrict__ qkv, const short* __restrict__ ktr,
               const short* __restrict__ vt,
               const u64* __restrict__ maskS, const u64* __restrict__ maskL,
               const u64* __restrict__ maskG, short* __restrict__ out) {
    const int tid = threadIdx.x;
    const int w = tid >> 6, lane = tid & 63, l15 = lane & 15, quad = lane >> 4;
    const int p = blockIdx.x;                       // 512 blocks
    const int g_ = (p & 7) + 8 * (p >> 6);          // (b,h) group, XCD-swizzled
    const int qt = ((p >> 3) & 7) * 2 + (w >> 2);   // waves 0-3: qt, 4-7: qt+1
    const int b = g_ >> 3, h = g_ & 7;
    const int q = qt * 64 + (w & 3) * 16 + l15;

    __shared__ __align__(16) short Ks[128 * 64];    // 128 keys (permuted) x 64 d
    __shared__ __align__(16) short Vs[128 * 64];    // 2 halves: 64 d x 64 keys

    short8 qf[2];
    {
        const short* qrow = qkv + ((size_t)(b * SEQ + q) * 1536) + h * 64;
#pragma unroll
        for (int ks = 0; ks < 2; ks++)
            qf[ks] = *(const short8*)(qrow + ks * 32 + quad * 8);
    }
    const u64* mrow = (h < 4) ? (maskS + ((size_t)b * SEQ + q) * 16)
                   : (h < 6) ? (maskL + ((size_t)b * SEQ + q) * 16)
                   :           (maskG + (size_t)b * 16);

    f32x4 of[4];
#pragma unroll
    for (int mt = 0; mt < 4; mt++) of[mt] = (f32x4){0.f, 0.f, 0.f, 0.f};
    float ls0 = 0.f, ls1 = 0.f;

    const int r_in = lane >> 3, c8 = lane & 7;
    const int swz = (c8 ^ r_in) << 3;   // chunk-invariant staging swizzle
    const short* kbase = ktr + ((size_t)(b * NH + h) * SEQ) * HD + swz;
    const short* vp = vt + ((size_t)((b * NH + h) * HD) + r_in) * SEQ + swz;
    const int fsw = (l15 & 7);

    for (int kt = 0; kt < SEQ; kt += 128) {
#pragma unroll
        for (int rep = 0; rep < 2; rep++) {         // K: permuted rows, 8 waves
            int c = rep * 8 + w;
            int pr = c * 8 + r_in;                  // physical staged row
            int pt = pr & 63;
            int key = (pr & 64) | (pt & 32) | (((pt >> 2) & 3) << 3)
                    | (((pt >> 4) & 1) << 2) | (pt & 3);
            gll16(kbase + (size_t)(kt + key) * HD, (char*)Ks + c * 1024);
        }
#pragma unroll
        for (int rep = 0; rep < 2; rep++) {         // V: plain, 2 halves x 8
            int v = rep * 8 + w;
            gll16(vp + (size_t)((v & 7) * 8) * SEQ + kt + (v >> 3) * 64,
                  (char*)Vs + v * 1024);
        }
        VM2();              // own K loads done (V pair still in flight)
        BAR(); SCHED0();    // all K resident

        short8 pfrags[2][2];
#pragma unroll
        for (int t = 0; t < 2; t++) {
            // S^T sub-tile (64 permuted keys x 16 q) — reads Ks only
            f32x4 sa[4];
#pragma unroll
            for (int g = 0; g < 4; g++) sa[g] = (f32x4){0.f, 0.f, 0.f, 0.f};
#pragma unroll
            for (int ks = 0; ks < 2; ks++) {
                const int dblk = ks * 4 + quad;
#pragma unroll
                for (int g = 0; g < 4; g++) {
                    int row = t * 64 + g * 16 + l15;
                    short8 kf = *(const short8*)((const char*)Ks + row * 128 + ((dblk ^ fsw) << 4));
                    sa[g] = __builtin_amdgcn_mfma_f32_16x16x32_bf16(kf, qf[ks], sa[g], 0, 0, 0);
                }
            }
            // masked softmax numerator (max-free); logical bitpos for slot
            // (g,quad,r) is quad*8 + (g>>1)*32 + (g&1)*4 + r
            u64 mw = mrow[(kt >> 6) + t];
            if ((q >> 6) == (kt >> 6) + t) mw |= 1ull << (q & 63);
            u64 mq2 = mw >> (quad * 8);
            unsigned mlo = (unsigned)mq2, mhi = (unsigned)(mq2 >> 32);
            float pv[4][4];
#pragma unroll
            for (int g = 0; g < 4; g++) {
                unsigned mg = ((g & 2) ? mhi : mlo) >> ((g & 1) * 4);
#pragma unroll
                for (int r = 0; r < 4; r++) {
                    float e = fexp2(sa[g][r] * EXP2SC);
                    e = ((mg >> r) & 1u) ? e : 0.f;
                    pv[g][r] = e;
                    if (g & 1) ls1 += e; else ls0 += e;
                }
            }
            // pack C reg-pairs directly into K=32 B-frags (no shuffles)
#pragma unroll
            for (int g32 = 0; g32 < 2; g32++) {
                uint4v pk;
                pk[0] = __builtin_amdgcn_perm(__float_as_uint(pv[2 * g32][1]),
                                              __float_as_uint(pv[2 * g32][0]), 0x07060302u);
                pk[1] = __builtin_amdgcn_perm(__float_as_uint(pv[2 * g32][3]),
                                              __float_as_uint(pv[2 * g32][2]), 0x07060302u);
                pk[2] = __builtin_amdgcn_perm(__float_as_uint(pv[2 * g32 + 1][1]),
                                              __float_as_uint(pv[2 * g32 + 1][0]), 0x07060302u);
                pk[3] = __builtin_amdgcn_perm(__float_as_uint(pv[2 * g32 + 1][3]),
                                              __float_as_uint(pv[2 * g32 + 1][2]), 0x07060302u);
                pfrags[t][g32] = __builtin_bit_cast(short8, pk);
            }
        }

        VM0();              // own V loads done (arrived under QK^T/softmax)
        BAR(); SCHED0();    // all V resident

        // O^T += V^T . P^T  (16x16x32, 8 MFMAs per sub-tile)
#pragma unroll
        for (int t = 0; t < 2; t++)
#pragma unroll
            for (int g32 = 0; g32 < 2; g32++) {
                const int u = g32 * 4 + quad;
#pragma unroll
                for (int mt = 0; mt < 4; mt++) {
                    int row = mt * 16 + l15;
                    short8 vf = *(const short8*)((const char*)Vs + t * 8192 + row * 128 + ((u ^ fsw) << 4));
                    of[mt] = __builtin_amdgcn_mfma_f32_16x16x32_bf16(vf, pfrags[t][g32], of[mt], 0, 0, 0);
                }
            }
        BAR(); SCHED0();    // all reads done before next tile's staging
    }
    float lsum = ls0 + ls1;
    lsum += __shfl_xor(lsum, 16);
    lsum += __shfl_xor(lsum, 32);
    float inv = 1.f / lsum;              // diagonal always allowed -> lsum > 0
#pragma unroll
    for (int mt = 0; mt < 4; mt++) {
        short4v pk;
#pragma unroll
        for (int r = 0; r < 4; r++) pk[r] = f2bf(of[mt][r] * inv);
        *(short4v*)(out + ((size_t)(b * SEQ + q) * HDIM) + h * 64 + mt * 16 + quad * 4) = pk;
    }
}

// ---------------------------------------------------------------------------
__global__ __launch_bounds__(256) void final_bn(const short* __restrict__ X,
                                                const float* __restrict__ g,
                                                const float* __restrict__ bb,
                                                float* __restrict__ out) {
    int h = blockIdx.x * 256 + threadIdx.x;
    if (h >= HDIM) return;
    float vals[BATCH];
    float m = 0.f;
#pragma unroll
    for (int b = 0; b < BATCH; b++) {
        vals[b] = bf2f(X[(size_t)b * SEQ * HDIM + h]);
        m += vals[b];
    }
    m *= (1.f / BATCH);
    float v = 0.f;
#pragma unroll
    for (int b = 0; b < BATCH; b++) { float d = vals[b] - m; v += d * d; }
    v *= (1.f / BATCH);
    float inv = rsqrtf(v + EPS);
#pragma unroll
    for (int b = 0; b < BATCH; b++)
        out[b * HDIM + h] = (vals[b] - m) * inv * g[h] + bb[h];
}

// ---------------------------------------------------------------------------
extern "C" void kernel_launch(void* const* d_in, const int* in_sizes, int n_in,
                              void* d_out, int out_size, void* d_ws, size_t ws_size,
                              hipStream_t stream) {
    const float* nodes      = (const float*)d_in[0];
    const int*   dist       = (const int*)  d_in[1];
    const float* dense_w    = (const float*)d_in[2];
    const float* dense_b    = (const float*)d_in[3];
    const float* dense_ln_g = (const float*)d_in[4];
    const float* dense_ln_b = (const float*)d_in[5];
    const float* qkv_w      = (const float*)d_in[6];
    const float* qkv_b      = (const float*)d_in[7];
    const float* out_w      = (const float*)d_in[8];
    const float* out_b      = (const float*)d_in[9];
    const float* ln1_g      = (const float*)d_in[10];
    const float* ln1_b      = (const float*)d_in[11];
    const float* ffn_w1     = (const float*)d_in[12];
    const float* ffn_b1     = (const float*)d_in[13];
    const float* ffn_w2     = (const float*)d_in[14];
    const float* ffn_b2     = (const float*)d_in[15];
    const float* ln2_g      = (const float*)d_in[16];
    const float* ln2_b      = (const float*)d_in[17];
    const float* bn_g       = (const float*)d_in[18];
    const float* bn_b       = (const float*)d_in[19];
    float* out = (float*)d_out;

    const int M = BATCH * SEQ;                         // 8192
    const size_t MB = 1024 * 1024;
    char* ws = (char*)d_ws;
    short* Wd   = (short*)(ws + 0 * MB);
    short* Wqkv = (short*)(ws + 1 * MB);
    short* Wo   = (short*)(ws + 9 * MB);
    short* W1   = (short*)(ws + 13 * MB);
    short* W2   = (short*)(ws + 18 * MB);
    u64*   mS   = (u64*)(ws + 23 * MB);
    u64*   mL   = (u64*)(ws + 24 * MB);
    u64*   mG   = (u64*)(ws + 25 * MB);
    short* X    = (short*)(ws + 26 * MB);
    short* QKV  = (short*)(ws + 34 * MB);
    short* Vt   = (short*)(ws + 58 * MB);
    short* AT   = (short*)(ws + 66 * MB);
    short* Kt   = (short*)(ws + 74 * MB);
    short* XT   = QKV;

    prep_all<<<PREP_W + PREP_N + BATCH * SEQ, 256, 0, stream>>>(
        dense_w, Wd, qkv_w, Wqkv, out_w, Wo, ffn_w1, W1, ffn_w2, W2,
        nodes, XT, dist, mS, mL, mG);

    // dense projection + dense LN, fused
    gemm_ln<IDIM, false><<<M / 32, 512, 0, stream>>>(
        XT, Wd, dense_b, nullptr, dense_ln_g, dense_ln_b, X);

    for (int l = 0; l < LAYERS; l++) {
        const short* wqkv = Wqkv + (size_t)l * 3 * HDIM * HDIM;
        const float* bqkv = qkv_b + (size_t)l * 3 * HDIM;
        const short* wo   = Wo + (size_t)l * HDIM * HDIM;
        const float* bo   = out_b + (size_t)l * HDIM;
        const short* w1   = W1 + (size_t)l * FF * HDIM;
        const float* b1   = ffn_b1 + (size_t)l * FF;
        const short* w2   = W2 + (size_t)l * HDIM * FF;
        const float* b2   = ffn_b2 + (size_t)l * HDIM;

        gemm_bf16<128, 128><<<dim3(3 * HDIM / 128, M / 128), 256, 0, stream>>>(
            X, wqkv, bqkv, QKV, Vt, Kt, M, 3 * HDIM, HDIM, 0);
        attn_mfma<<<512, 512, 0, stream>>>(QKV, Kt, Vt, mS, mL, mG, AT);
        // attn out projection + residual + LN1, fused
        gemm_ln<HDIM, true><<<M / 32, 512, 0, stream>>>(
            AT, wo, bo, X, ln1_g + l * HDIM, ln1_b + l * HDIM, X);
        // FFN up + relu + down + residual + LN2, fully fused (no F1 buffer)
        fused_ffn<<<M / 32, 512, 0, stream>>>(
            X, w1, b1, w2, b2, ln2_g + l * HDIM, ln2_b + l * HDIM, X);
    }
    final_bn<<<(HDIM + 255) / 256, 256, 0, stream>>>(X, bn_g, bn_b, out);
}